// Round 7
// baseline (523.478 us; speedup 1.0000x reference)
//
#include <hip/hip_runtime.h>
#include <hip/hip_bf16.h>
#include <math.h>

// Sizes (fixed by the problem)
#define B 64
#define T 64
#define E_ENC 1024
#define EMB 512
#define D 512
#define L 32
#define S 31
#define A 512
#define V 30000
#define KSZ 7
#define KC (D * KSZ)   // 3584 = conv GEMM K

typedef __attribute__((ext_vector_type(8))) short bf16x8;
typedef __attribute__((ext_vector_type(4))) float f32x4;

__device__ __forceinline__ unsigned short f2bf(float f) {
  union { float f; unsigned int u; } x; x.f = f;
  unsigned int r = (x.u + 0x7fffu + ((x.u >> 16) & 1u)) >> 16;
  return (unsigned short)r;
}

__device__ __forceinline__ void gload_lds16(const void* g, void* l) {
  __builtin_amdgcn_global_load_lds(
      (const __attribute__((address_space(1))) unsigned int*)g,
      (__attribute__((address_space(3))) unsigned int*)l, 16, 0, 0);
}

// ---------------------------------------------------------------------------
// wv[e] = sum_a Wp[a]*Wenc[a,e];  c0 = sum_a benc[a]*Wp[a]
__global__ void k_wv(const float* __restrict__ Wenc, const float* __restrict__ Wp,
                     const float* __restrict__ benc, float* __restrict__ wv,
                     float* __restrict__ c0) {
  __shared__ float red[256];
  int e = blockIdx.x * 256 + threadIdx.x;
  float s = 0.f;
  for (int a = 0; a < A; ++a) s += Wp[a] * Wenc[(size_t)a * E_ENC + e];
  wv[e] = s;
  if (blockIdx.x == 0) {
    int t = threadIdx.x;
    float v = Wp[t] * benc[t] + Wp[t + 256] * benc[t + 256];
    red[t] = v;
    __syncthreads();
    for (int off = 128; off > 0; off >>= 1) {
      if (t < off) red[t] += red[t + off];
      __syncthreads();
    }
    if (t == 0) c0[0] = red[0];
  }
}

// ---------------------------------------------------------------------------
// Per-b: enc_mean[b,:], fscore -> softmax over t -> ctx (bf16)
__global__ void k_mean_ctx(const float* __restrict__ features, const float* __restrict__ wv,
                           const float* __restrict__ c0, float* __restrict__ enc_mean,
                           unsigned short* __restrict__ ctxb) {
  int b = blockIdx.x, tid = threadIdx.x;
  const float* fb = features + (size_t)b * T * E_ENC;
  __shared__ float s_attw[T];

  float m0 = 0, m1 = 0, m2 = 0, m3 = 0;
  for (int t = 0; t < T; ++t) {
    const float* r = fb + t * E_ENC;
    m0 += r[tid]; m1 += r[tid + 256]; m2 += r[tid + 512]; m3 += r[tid + 768];
  }
  size_t eb = (size_t)b * E_ENC;
  enc_mean[eb + tid]       = m0 * (1.f / 64.f);
  enc_mean[eb + tid + 256] = m1 * (1.f / 64.f);
  enc_mean[eb + tid + 512] = m2 * (1.f / 64.f);
  enc_mean[eb + tid + 768] = m3 * (1.f / 64.f);

  {
    int t = tid >> 2, part = tid & 3;
    const float* r = fb + t * E_ENC + part * 256;
    const float* wp = wv + part * 256;
    float s = 0.f;
    for (int e = 0; e < 256; e += 4) {
      float4 f4 = *(const float4*)(r + e);
      float4 w4 = *(const float4*)(wp + e);
      s += f4.x * w4.x + f4.y * w4.y + f4.z * w4.z + f4.w * w4.w;
    }
    s += __shfl_xor(s, 1);
    s += __shfl_xor(s, 2);
    if (part == 0) s_attw[t] = s + c0[0];
  }
  __syncthreads();
  if (tid < 64) {
    float v = s_attw[tid];
    float mx = v;
    #pragma unroll
    for (int off = 32; off > 0; off >>= 1) mx = fmaxf(mx, __shfl_xor(mx, off));
    float e = expf(v - mx);
    float sm = e;
    #pragma unroll
    for (int off = 32; off > 0; off >>= 1) sm += __shfl_xor(sm, off);
    s_attw[tid] = e / sm;
  }
  __syncthreads();
  float ca = 0, cb = 0, cc = 0, cd = 0;
  for (int t = 0; t < T; ++t) {
    float w = s_attw[t];
    const float* r = fb + t * E_ENC;
    ca += w * r[tid]; cb += w * r[tid + 256]; cc += w * r[tid + 512]; cd += w * r[tid + 768];
  }
  ctxb[eb + tid]       = f2bf(ca);
  ctxb[eb + tid + 256] = f2bf(cb);
  ctxb[eb + tid + 512] = f2bf(cc);
  ctxb[eb + tid + 768] = f2bf(cd);
}

// ---------------------------------------------------------------------------
// base1[b,d] = b1[d] + enc_mean[b,:1024] . W1[d,:1024]
__global__ void k_base1(const float* __restrict__ enc_mean, const float* __restrict__ W1,
                        const float* __restrict__ b1, float* __restrict__ base1) {
  __shared__ float em[E_ENC];
  int b = blockIdx.x, tid = threadIdx.x;
  for (int i = tid; i < E_ENC; i += 256) em[i] = enc_mean[(size_t)b * E_ENC + i];
  __syncthreads();
  for (int d = tid; d < D; d += 256) {
    const float* w = W1 + (size_t)d * (E_ENC + EMB);
    float acc = 0.f;
    for (int e = 0; e < E_ENC; e += 4) {
      float4 w4 = *(const float4*)(w + e);
      acc += w4.x * em[e] + w4.y * em[e + 1] + w4.z * em[e + 2] + w4.w * em[e + 3];
    }
    base1[b * D + d] = acc + b1[d];
  }
}

// ---------------------------------------------------------------------------
// Gather embedding rows per caption token -> bf16 Xe[2048][512]
__global__ void k_gather_emb(const float* __restrict__ embed_W,
                             const int* __restrict__ captions,
                             unsigned short* __restrict__ Xe) {
  int g = blockIdx.x, tid = threadIdx.x;
  int cap = captions[g];
  const float* src = embed_W + (size_t)cap * EMB;
  float2 v = *(const float2*)(src + tid * 2);
  unsigned int pk = (unsigned int)f2bf(v.x) | ((unsigned int)f2bf(v.y) << 16);
  *(unsigned int*)(Xe + (size_t)g * EMB + tid * 2) = pk;
}

// W1 decode-half conversion: w1db[d][c] = bf16(W1[d][1024+c])
__global__ void k_cvt_w1d(const float* __restrict__ W1, unsigned short* __restrict__ w1db) {
  int d = blockIdx.x, tid = threadIdx.x;
  float2 v = *(const float2*)(W1 + (size_t)d * (E_ENC + EMB) + E_ENC + tid * 2);
  unsigned int pk = (unsigned int)f2bf(v.x) | ((unsigned int)f2bf(v.y) << 16);
  *(unsigned int*)(w1db + (size_t)d * EMB + tid * 2) = pk;
}

// ---------------------------------------------------------------------------
// x1 GEMM: x1[g][d] = base1[g>>5][d] + Xe[g,:] . w1db[d,:]   M=2048,N=512,K=512
__global__ __launch_bounds__(256) void k_x1_mfma(
    const unsigned short* __restrict__ Xe, const unsigned short* __restrict__ w1db,
    const float* __restrict__ base1, float* __restrict__ x1) {
  __shared__ __align__(16) unsigned short As[64 * 64];  // 8 KB
  __shared__ __align__(16) unsigned short Bs[64 * 64];  // 8 KB
  int c0 = blockIdx.x * 64, g0 = blockIdx.y * 64;
  int tid = threadIdx.x, lane = tid & 63, wave = tid >> 6;
  int wr = wave >> 1, wc = wave & 1;
  int rsel = lane & 15, hi = lane >> 4;

  f32x4 acc[2][2];
  #pragma unroll
  for (int m = 0; m < 2; ++m)
    #pragma unroll
    for (int n = 0; n < 2; ++n) acc[m][n] = (f32x4){0.f, 0.f, 0.f, 0.f};

  int r1 = tid >> 3, s1 = tid & 7;
  int sw = (s1 ^ (r1 & 7)) * 8;
  const unsigned short* gA1 = Xe + (size_t)(g0 + r1) * EMB + sw;
  const unsigned short* gA2 = Xe + (size_t)(g0 + r1 + 32) * EMB + sw;
  const unsigned short* gB1 = w1db + (size_t)(c0 + r1) * EMB + sw;
  const unsigned short* gB2 = w1db + (size_t)(c0 + r1 + 32) * EMB + sw;
  unsigned short* aD1 = As + wave * 512;
  unsigned short* aD2 = As + 2048 + wave * 512;
  unsigned short* bD1 = Bs + wave * 512;
  unsigned short* bD2 = Bs + 2048 + wave * 512;

  int slot0 = hi ^ (rsel & 7);
  int slot1 = (4 + hi) ^ (rsel & 7);

  for (int kt = 0; kt < EMB / 64; ++kt) {
    gload_lds16(gA1, aD1);
    gload_lds16(gA2, aD2);
    gload_lds16(gB1, bD1);
    gload_lds16(gB2, bD2);
    gA1 += 64; gA2 += 64; gB1 += 64; gB2 += 64;
    __syncthreads();

    bf16x8 af[2][2], bfr[2][2];
    #pragma unroll
    for (int m = 0; m < 2; ++m) {
      int rowA = (wr * 32 + m * 16 + rsel) * 64;
      af[m][0] = *(const bf16x8*)(As + rowA + slot0 * 8);
      af[m][1] = *(const bf16x8*)(As + rowA + slot1 * 8);
    }
    #pragma unroll
    for (int n = 0; n < 2; ++n) {
      int rowB = (wc * 32 + n * 16 + rsel) * 64;
      bfr[n][0] = *(const bf16x8*)(Bs + rowB + slot0 * 8);
      bfr[n][1] = *(const bf16x8*)(Bs + rowB + slot1 * 8);
    }
    #pragma unroll
    for (int m = 0; m < 2; ++m)
      #pragma unroll
      for (int n = 0; n < 2; ++n) {
        acc[m][n] = __builtin_amdgcn_mfma_f32_16x16x32_bf16(af[m][0], bfr[n][0], acc[m][n], 0, 0, 0);
        acc[m][n] = __builtin_amdgcn_mfma_f32_16x16x32_bf16(af[m][1], bfr[n][1], acc[m][n], 0, 0, 0);
      }
    __syncthreads();
  }

  #pragma unroll
  for (int m = 0; m < 2; ++m)
    #pragma unroll
    for (int i = 0; i < 4; ++i) {
      int g = g0 + wr * 32 + m * 16 + hi * 4 + i;
      const float* br = base1 + (size_t)(g >> 5) * D;
      float* xr = x1 + (size_t)g * D;
      #pragma unroll
      for (int n = 0; n < 2; ++n) {
        int c = c0 + wc * 32 + n * 16 + rsel;
        xr[c] = acc[m][n][i] + br[c];
      }
    }
}

// ---------------------------------------------------------------------------
// im2col: Xc[g][k*512+dp] = (l+k-6 >= 0) ? x[b][l+k-6][dp] : 0   (bf16)
__global__ void k_im2col(const float* __restrict__ x, unsigned short* __restrict__ Xc) {
  int g = blockIdx.x, tid = threadIdx.x;
  int b = g >> 5, l = g & 31;
  unsigned short* row = Xc + (size_t)g * KC;
  const float* xb = x + (size_t)b * L * D;
  int d = tid * 2;
  #pragma unroll
  for (int k = 0; k < KSZ; ++k) {
    int lp = l + k - 6;
    unsigned int pk = 0;
    if (lp >= 0) {
      float2 v = *(const float2*)(xb + (size_t)lp * D + d);
      pk = (unsigned int)f2bf(v.x) | ((unsigned int)f2bf(v.y) << 16);
    }
    *(unsigned int*)(row + k * 512 + d) = pk;
  }
}

// ---------------------------------------------------------------------------
// conv weight reorder+convert: wb[c][k*512+dp] = bf16(w[c][dp*7+k])
__global__ void k_cvt_wconv(const float* __restrict__ w, unsigned short* __restrict__ wb) {
  __shared__ float row[KC];  // 14 KiB
  int c = blockIdx.x, tid = threadIdx.x;
  const float* wr = w + (size_t)c * KC;
  for (int i = tid; i < KC; i += 256) row[i] = wr[i];
  __syncthreads();
  unsigned short* ob = wb + (size_t)c * KC;
  int dp = tid * 2;
  #pragma unroll
  for (int k = 0; k < KSZ; ++k) {
    unsigned int pk = (unsigned int)f2bf(row[dp * 7 + k]) |
                      ((unsigned int)f2bf(row[(dp + 1) * 7 + k]) << 16);
    *(unsigned int*)(ob + k * 512 + dp) = pk;
  }
}

// ---------------------------------------------------------------------------
// Conv GEMM: y[g][c] = bias[c] + Xc[g,:] . wb[c,:]   M=2048, N=1024, K=3584
// R5 geometry (64x64 tile, 512 blocks = 2/CU) + 2-phase LDS double-buffer:
// stage t+1 issued BEFORE compute(t); single vmcnt(0)+barrier per tile.
__global__ __launch_bounds__(256) void k_conv_mfma(
    const unsigned short* __restrict__ Xc, const unsigned short* __restrict__ wb,
    const float* __restrict__ bias, float* __restrict__ y) {
  __shared__ __align__(16) unsigned short As[2][64 * 64];  // 16 KB
  __shared__ __align__(16) unsigned short Bs[2][64 * 64];  // 16 KB
  int c0 = blockIdx.x * 64, g0 = blockIdx.y * 64;
  int tid = threadIdx.x, lane = tid & 63, wave = tid >> 6;
  int wr = wave >> 1, wc = wave & 1;
  int rsel = lane & 15, hi = lane >> 4;

  f32x4 acc[2][2];
  #pragma unroll
  for (int m = 0; m < 2; ++m)
    #pragma unroll
    for (int n = 0; n < 2; ++n) acc[m][n] = (f32x4){0.f, 0.f, 0.f, 0.f};

  int r1 = tid >> 3, s1 = tid & 7;
  int sw = (s1 ^ (r1 & 7)) * 8;              // swizzled global k-segment (shorts)
  const unsigned short* gA1 = Xc + (size_t)(g0 + r1) * KC + sw;
  const unsigned short* gA2 = Xc + (size_t)(g0 + r1 + 32) * KC + sw;
  const unsigned short* gB1 = wb + (size_t)(c0 + r1) * KC + sw;
  const unsigned short* gB2 = wb + (size_t)(c0 + r1 + 32) * KC + sw;

  int slot0 = hi ^ (rsel & 7);        // kk=0
  int slot1 = (4 + hi) ^ (rsel & 7);  // kk=1

  // prologue: stage kt=0 into buf 0
  gload_lds16(gA1, &As[0][wave * 512]);
  gload_lds16(gA2, &As[0][2048 + wave * 512]);
  gload_lds16(gB1, &Bs[0][wave * 512]);
  gload_lds16(gB2, &Bs[0][2048 + wave * 512]);
  gA1 += 64; gA2 += 64; gB1 += 64; gB2 += 64;
  __syncthreads();

  int cur = 0;
  for (int kt = 0; kt < KC / 64; ++kt) {
    if (kt + 1 < KC / 64) {
      int nb = cur ^ 1;
      gload_lds16(gA1, &As[nb][wave * 512]);
      gload_lds16(gA2, &As[nb][2048 + wave * 512]);
      gload_lds16(gB1, &Bs[nb][wave * 512]);
      gload_lds16(gB2, &Bs[nb][2048 + wave * 512]);
      gA1 += 64; gA2 += 64; gB1 += 64; gB2 += 64;
    }

    bf16x8 af[2][2], bfr[2][2];
    #pragma unroll
    for (int m = 0; m < 2; ++m) {
      int rowA = (wr * 32 + m * 16 + rsel) * 64;
      af[m][0] = *(const bf16x8*)(&As[cur][rowA + slot0 * 8]);
      af[m][1] = *(const bf16x8*)(&As[cur][rowA + slot1 * 8]);
    }
    #pragma unroll
    for (int n = 0; n < 2; ++n) {
      int rowB = (wc * 32 + n * 16 + rsel) * 64;
      bfr[n][0] = *(const bf16x8*)(&Bs[cur][rowB + slot0 * 8]);
      bfr[n][1] = *(const bf16x8*)(&Bs[cur][rowB + slot1 * 8]);
    }
    #pragma unroll
    for (int m = 0; m < 2; ++m)
      #pragma unroll
      for (int n = 0; n < 2; ++n) {
        acc[m][n] = __builtin_amdgcn_mfma_f32_16x16x32_bf16(af[m][0], bfr[n][0], acc[m][n], 0, 0, 0);
        acc[m][n] = __builtin_amdgcn_mfma_f32_16x16x32_bf16(af[m][1], bfr[n][1], acc[m][n], 0, 0, 0);
      }
    __syncthreads();   // drains the t+1 stage (vmcnt 0) + protects buf reuse
    cur ^= 1;
  }

  float bv[2];
  #pragma unroll
  for (int n = 0; n < 2; ++n) bv[n] = bias[c0 + wc * 32 + n * 16 + rsel];
  #pragma unroll
  for (int m = 0; m < 2; ++m)
    #pragma unroll
    for (int i = 0; i < 4; ++i) {
      int g = g0 + wr * 32 + m * 16 + hi * 4 + i;
      float* yr = y + (size_t)g * 1024;
      #pragma unroll
      for (int n = 0; n < 2; ++n)
        yr[c0 + wc * 32 + n * 16 + rsel] = acc[m][n][i] + bv[n];
    }
}

// ---------------------------------------------------------------------------
// GLU: xout[g][d] = y[g][d] * sigmoid(y[g][d+512]) + xres[g][d]
__global__ void k_glu(const float* __restrict__ y, const float* __restrict__ xres,
                      float* __restrict__ xout) {
  int idx = blockIdx.x * 256 + threadIdx.x;  // 2048*128
  int g = idx >> 7, d4 = (idx & 127) << 2;
  const float* yr = y + (size_t)g * 1024;
  float4 a = *(const float4*)(yr + d4);
  float4 bq = *(const float4*)(yr + 512 + d4);
  float4 xr = *(const float4*)(xres + (size_t)g * 512 + d4);
  float4 o;
  o.x = a.x / (1.f + expf(-bq.x)) + xr.x;
  o.y = a.y / (1.f + expf(-bq.y)) + xr.y;
  o.z = a.z / (1.f + expf(-bq.z)) + xr.z;
  o.w = a.w / (1.f + expf(-bq.w)) + xr.w;
  *(float4*)(xout + (size_t)g * 512 + d4) = o;
}

// Layer-2 GLU: writes bf16 x3 directly.
__global__ void k_glu_bf16(const float* __restrict__ y, const float* __restrict__ xres,
                           unsigned short* __restrict__ xout) {
  int idx = blockIdx.x * 256 + threadIdx.x;
  int g = idx >> 7, d4 = (idx & 127) << 2;
  const float* yr = y + (size_t)g * 1024;
  float4 a = *(const float4*)(yr + d4);
  float4 bq = *(const float4*)(yr + 512 + d4);
  float4 xr = *(const float4*)(xres + (size_t)g * 512 + d4);
  ushort4 o;
  o.x = f2bf(a.x / (1.f + expf(-bq.x)) + xr.x);
  o.y = f2bf(a.y / (1.f + expf(-bq.y)) + xr.y);
  o.z = f2bf(a.z / (1.f + expf(-bq.z)) + xr.z);
  o.w = f2bf(a.w / (1.f + expf(-bq.w)) + xr.w);
  *(ushort4*)(xout + (size_t)g * 512 + d4) = o;
}

// ---------------------------------------------------------------------------
// cbase[b,v] = b2[v] + ctx[b,:1024] . W2[v,:1024]  as bf16 MFMA.
__global__ __launch_bounds__(256) void k_cbase_mfma(
    const unsigned short* __restrict__ ctxb,  // [64][1024] bf16
    const float* __restrict__ W2,             // [30000][1536] fp32
    const float* __restrict__ b2, float* __restrict__ cbase) {
  __shared__ __align__(16) unsigned short As[64 * 64];    // 8 KB
  __shared__ __align__(16) unsigned short Bs[128 * 64];   // 16 KB
  int v0 = blockIdx.x * 128;
  int tid = threadIdx.x, lane = tid & 63, wave = tid >> 6;
  int rsel = lane & 15, hi = lane >> 4;
  int wc = wave;

  f32x4 acc[4][2];
  #pragma unroll
  for (int m = 0; m < 4; ++m)
    #pragma unroll
    for (int n = 0; n < 2; ++n) acc[m][n] = (f32x4){0.f, 0.f, 0.f, 0.f};

  int ra1 = tid >> 3, sa = tid & 7;
  int ra2 = ra1 + 32;
  const unsigned short* gA1 = ctxb + (size_t)ra1 * 1024 + (sa ^ (ra1 & 7)) * 8;
  const unsigned short* gA2 = ctxb + (size_t)ra2 * 1024 + (sa ^ (ra2 & 7)) * 8;
  unsigned short* aD1 = As + wave * 512;
  unsigned short* aD2 = As + 2048 + wave * 512;

  const float* gB[4];
  int bofs[4];
  #pragma unroll
  for (int p = 0; p < 4; ++p) {
    int row = p * 32 + (tid >> 3);
    int seg = tid & 7;
    int vr = v0 + row; if (vr > V - 1) vr = V - 1;
    gB[p] = W2 + (size_t)vr * (E_ENC + D) + seg * 8;
    bofs[p] = row * 64 + (seg ^ (row & 7)) * 8;
  }

  for (int kt = 0; kt < 16; ++kt) {
    gload_lds16(gA1, aD1);
    gload_lds16(gA2, aD2);
    gA1 += 64; gA2 += 64;
    #pragma unroll
    for (int p = 0; p < 4; ++p) {
      float4 f0 = *(const float4*)(gB[p]);
      float4 f1 = *(const float4*)(gB[p] + 4);
      gB[p] += 64;
      bf16x8 o;
      o[0] = (short)f2bf(f0.x); o[1] = (short)f2bf(f0.y);
      o[2] = (short)f2bf(f0.z); o[3] = (short)f2bf(f0.w);
      o[4] = (short)f2bf(f1.x); o[5] = (short)f2bf(f1.y);
      o[6] = (short)f2bf(f1.z); o[7] = (short)f2bf(f1.w);
      *(bf16x8*)(Bs + bofs[p]) = o;
    }
    __syncthreads();

    bf16x8 af[4][2], bfr[2][2];
    #pragma unroll
    for (int m = 0; m < 4; ++m) {
      int rowA = (m * 16 + rsel) * 64;
      #pragma unroll
      for (int kk = 0; kk < 2; ++kk)
        af[m][kk] = *(const bf16x8*)(As + rowA + ((kk * 4 + hi) ^ (rsel & 7)) * 8);
    }
    #pragma unroll
    for (int n = 0; n < 2; ++n) {
      int rowB = (wc * 32 + n * 16 + rsel) * 64;
      #pragma unroll
      for (int kk = 0; kk < 2; ++kk)
        bfr[n][kk] = *(const bf16x8*)(Bs + rowB + ((kk * 4 + hi) ^ (rsel & 7)) * 8);
    }
    #pragma unroll
    for (int kk = 0; kk < 2; ++kk)
      #pragma unroll
      for (int m = 0; m < 4; ++m)
        #pragma unroll
        for (int n = 0; n < 2; ++n)
          acc[m][n] = __builtin_amdgcn_mfma_f32_16x16x32_bf16(af[m][kk], bfr[n][kk], acc[m][n], 0, 0, 0);
    __syncthreads();
  }

  #pragma unroll
  for (int n = 0; n < 2; ++n) {
    int v = v0 + wc * 32 + n * 16 + rsel;
    if (v >= V) continue;
    float bias = b2[v];
    #pragma unroll
    for (int m = 0; m < 4; ++m)
      #pragma unroll
      for (int i = 0; i < 4; ++i) {
        int b = m * 16 + hi * 4 + i;
        cbase[(size_t)b * V + v] = acc[m][n][i] + bias;
      }
  }
}

// ---------------------------------------------------------------------------
// W2 decode-half conversion: y[v][c] = bf16(W2[v][1024+c])
__global__ void k_cvt_w2d(const float* __restrict__ W2, unsigned short* __restrict__ y) {
  int i = blockIdx.x * 256 + threadIdx.x;   // 30000*128 groups of 4
  int row = i >> 7, c = (i & 127) << 2;
  float4 f = *(const float4*)(W2 + (size_t)row * (E_ENC + D) + E_ENC + c);
  ushort4 o;
  o.x = f2bf(f.x); o.y = f2bf(f.y); o.z = f2bf(f.z); o.w = f2bf(f.w);
  *(ushort4*)(y + (size_t)row * D + c) = o;
}

// ---------------------------------------------------------------------------
// logits[b,s,v] = cbase[b,v] + x3[b,s,:] . W2d[v,:]
// M=2048, N=30000, K=512. Tile 128g x 128v, BK=64, swizzle + XCD remap
// (both counter-verified) + 2-phase LDS double-buffer (counted-drain overlap).
__global__ __launch_bounds__(256) void k_logits_mfma(
    const unsigned short* __restrict__ Ab,   // x3 bf16 [2048][512]
    const unsigned short* __restrict__ Bb,   // W2d bf16 [30000][512]
    const float* __restrict__ cbase, float* __restrict__ out) {
  __shared__ __align__(16) unsigned short As[2][128 * 64];  // 32 KB
  __shared__ __align__(16) unsigned short Bs[2][128 * 64];  // 32 KB
  int flat = blockIdx.x;                  // 3760 = 8 * 470
  int ord = (flat & 7) * 470 + (flat >> 3);
  int v0 = (ord >> 4) * 128, g0 = (ord & 15) * 128;
  int tid = threadIdx.x, lane = tid & 63, wave = tid >> 6;
  int wr = wave >> 1, wc = wave & 1;
  int rsel = lane & 15, hi = lane >> 4;

  f32x4 acc[4][4];
  #pragma unroll
  for (int m = 0; m < 4; ++m)
    #pragma unroll
    for (int n = 0; n < 4; ++n) acc[m][n] = (f32x4){0.f, 0.f, 0.f, 0.f};

  int r0 = tid >> 3, slot = tid & 7;
  int swseg = (slot ^ (r0 & 7)) * 8;      // (r0+32p)&7 == r0&7 (local-row swizzle)
  const unsigned short* gA[4];
  const unsigned short* gB[4];
  #pragma unroll
  for (int p = 0; p < 4; ++p) {
    gA[p] = Ab + (size_t)(g0 + r0 + 32 * p) * 512 + swseg;
    int rB = v0 + r0 + 32 * p; if (rB > V - 1) rB = V - 1;
    gB[p] = Bb + (size_t)rB * 512 + swseg;
  }

  // prologue: stage kt=0 into buf 0
  #pragma unroll
  for (int p = 0; p < 4; ++p) {
    gload_lds16(gA[p], &As[0][p * 2048 + wave * 512]);
    gload_lds16(gB[p], &Bs[0][p * 2048 + wave * 512]);
    gA[p] += 64; gB[p] += 64;
  }
  __syncthreads();

  int cur = 0;
  for (int kt = 0; kt < 8; ++kt) {
    if (kt + 1 < 8) {
      int nb = cur ^ 1;
      #pragma unroll
      for (int p = 0; p < 4; ++p) {
        gload_lds16(gA[p], &As[nb][p * 2048 + wave * 512]);
        gload_lds16(gB[p], &Bs[nb][p * 2048 + wave * 512]);
        gA[p] += 64; gB[p] += 64;
      }
    }

    bf16x8 af[4][2], bfr[4][2];
    #pragma unroll
    for (int m = 0; m < 4; ++m) {
      int rowA = (wr * 64 + m * 16 + rsel) * 64;
      #pragma unroll
      for (int kk = 0; kk < 2; ++kk)
        af[m][kk] = *(const bf16x8*)(&As[cur][rowA + (((kk * 4 + hi) ^ (rsel & 7)) * 8)]);
    }
    #pragma unroll
    for (int n = 0; n < 4; ++n) {
      int rowB = (wc * 64 + n * 16 + rsel) * 64;
      #pragma unroll
      for (int kk = 0; kk < 2; ++kk)
        bfr[n][kk] = *(const bf16x8*)(&Bs[cur][rowB + (((kk * 4 + hi) ^ (rsel & 7)) * 8)]);
    }
    #pragma unroll
    for (int kk = 0; kk < 2; ++kk)
      #pragma unroll
      for (int m = 0; m < 4; ++m)
        #pragma unroll
        for (int n = 0; n < 4; ++n)
          acc[m][n] = __builtin_amdgcn_mfma_f32_16x16x32_bf16(af[m][kk], bfr[n][kk], acc[m][n], 0, 0, 0);
    __syncthreads();   // drains the t+1 stage + protects buffer reuse
    cur ^= 1;
  }

  #pragma unroll
  for (int m = 0; m < 4; ++m) {
    #pragma unroll
    for (int i = 0; i < 4; ++i) {
      int g = g0 + wr * 64 + m * 16 + hi * 4 + i;
      int b = g >> 5, lt = g & 31;
      if (lt >= S) continue;
      size_t orow = ((size_t)b * S + lt) * V;
      const float* cb = cbase + (size_t)b * V;
      #pragma unroll
      for (int n = 0; n < 4; ++n) {
        int v = v0 + wc * 64 + n * 16 + rsel;
        if (v < V) out[orow + v] = acc[m][n][i] + cb[v];
      }
    }
  }
}

// ---------------------------------------------------------------------------
extern "C" void kernel_launch(void* const* d_in, const int* in_sizes, int n_in,
                              void* d_out, int out_size, void* d_ws, size_t ws_size,
                              hipStream_t stream) {
  const float* features = (const float*)d_in[0];
  const int*   captions = (const int*)d_in[1];
  const float* embed_W  = (const float*)d_in[3];
  const float* W1   = (const float*)d_in[4];
  const float* b1   = (const float*)d_in[5];
  const float* cw1  = (const float*)d_in[6];
  const float* cb1  = (const float*)d_in[7];
  const float* cw2  = (const float*)d_in[8];
  const float* cb2  = (const float*)d_in[9];
  const float* Wenc = (const float*)d_in[10];
  const float* benc = (const float*)d_in[11];
  const float* Wp   = (const float*)d_in[14];
  const float* W2   = (const float*)d_in[16];
  const float* b2   = (const float*)d_in[17];
  float* out = (float*)d_out;

  float* ws = (float*)d_ws;
  float* wv       = ws;                 // 1024
  float* c0       = ws + 1024;          // 16
  float* enc_mean = ws + 1040;          // 65536
  unsigned short* ctxb = (unsigned short*)(ws + 66576);  // 65536 bf16
  float* base1    = ws + 132112;        // 32768
  float* xA       = ws + 164880;        // 1048576 (x1; dead after GLU1)
  float* xB       = ws + 1213456;       // 1048576 (x2)
  float* y        = ws + 2262032;       // 2097152 (conv GEMM out; cbase aliases)
  float* cbase    = y;                  // 1920000 <= 2097152
  unsigned short* x3b  = (unsigned short*)xA;             // 1048576 bf16 (xA dead)
  unsigned short* Xc   = (unsigned short*)(ws + 4359184); // 7340032 bf16
  unsigned short* wbuf = (unsigned short*)(ws + 8029200); // 3670016 bf16
  unsigned short* W2d  = (unsigned short*)(ws + 9864208); // 15360000 bf16
  // Xe / w1db live inside the Xc region (free until im2col layer 1)
  unsigned short* Xe   = Xc;                 // 1048576 bf16
  unsigned short* w1db = Xc + 1048576;       // 262144 bf16
  // end: 17,544,208 floats = 70.2 MB (unchanged)

  hipLaunchKernelGGL(k_cvt_w2d,  dim3(15000),   dim3(256), 0, stream, W2, W2d);
  hipLaunchKernelGGL(k_wv,       dim3(4),       dim3(256), 0, stream, Wenc, Wp, benc, wv, c0);
  hipLaunchKernelGGL(k_mean_ctx, dim3(B),       dim3(256), 0, stream, features, wv, c0, enc_mean, ctxb);
  hipLaunchKernelGGL(k_base1,    dim3(B),       dim3(256), 0, stream, enc_mean, W1, b1, base1);

  // x1 = base1 + emb @ W1decᵀ  (MFMA)
  hipLaunchKernelGGL(k_gather_emb, dim3(2048),  dim3(256), 0, stream, embed_W, captions, Xe);
  hipLaunchKernelGGL(k_cvt_w1d,    dim3(512),   dim3(256), 0, stream, W1, w1db);
  hipLaunchKernelGGL(k_x1_mfma,    dim3(8, 32), dim3(256), 0, stream, Xe, w1db, base1, xA);

  // conv layer 1
  hipLaunchKernelGGL(k_cvt_wconv, dim3(1024),   dim3(256), 0, stream, cw1, wbuf);
  hipLaunchKernelGGL(k_im2col,    dim3(2048),   dim3(256), 0, stream, xA, Xc);
  hipLaunchKernelGGL(k_conv_mfma, dim3(16, 32), dim3(256), 0, stream, Xc, wbuf, cb1, y);
  hipLaunchKernelGGL(k_glu,       dim3(1024),   dim3(256), 0, stream, y, xA, xB);

  // conv layer 2
  hipLaunchKernelGGL(k_cvt_wconv, dim3(1024),   dim3(256), 0, stream, cw2, wbuf);
  hipLaunchKernelGGL(k_im2col,    dim3(2048),   dim3(256), 0, stream, xB, Xc);
  hipLaunchKernelGGL(k_conv_mfma, dim3(16, 32), dim3(256), 0, stream, Xc, wbuf, cb2, y);
  hipLaunchKernelGGL(k_glu_bf16,  dim3(1024),   dim3(256), 0, stream, y, xB, x3b);

  hipLaunchKernelGGL(k_cbase_mfma, dim3(235),   dim3(256), 0, stream, ctxb, W2, b2, cbase);
  hipLaunchKernelGGL(k_logits_mfma, dim3(3760), dim3(256), 0, stream, x3b, W2d, cbase, out);
}

// Round 8
// 424.936 us; speedup vs baseline: 1.2319x; 1.2319x over previous
//
#include <hip/hip_runtime.h>
#include <hip/hip_bf16.h>
#include <math.h>

// Sizes (fixed by the problem)
#define B 64
#define T 64
#define E_ENC 1024
#define EMB 512
#define D 512
#define L 32
#define S 31
#define A 512
#define V 30000
#define KSZ 7
#define KC (D * KSZ)   // 3584 = conv GEMM K

typedef __attribute__((ext_vector_type(8))) short bf16x8;
typedef __attribute__((ext_vector_type(4))) float f32x4;

__device__ __forceinline__ unsigned short f2bf(float f) {
  union { float f; unsigned int u; } x; x.f = f;
  unsigned int r = (x.u + 0x7fffu + ((x.u >> 16) & 1u)) >> 16;
  return (unsigned short)r;
}

__device__ __forceinline__ void gload_lds16(const void* g, void* l) {
  __builtin_amdgcn_global_load_lds(
      (const __attribute__((address_space(1))) unsigned int*)g,
      (__attribute__((address_space(3))) unsigned int*)l, 16, 0, 0);
}

// ---------------------------------------------------------------------------
// wv[e] = sum_a Wp[a]*Wenc[a,e];  c0 = sum_a benc[a]*Wp[a]
__global__ void k_wv(const float* __restrict__ Wenc, const float* __restrict__ Wp,
                     const float* __restrict__ benc, float* __restrict__ wv,
                     float* __restrict__ c0) {
  __shared__ float red[256];
  int e = blockIdx.x * 256 + threadIdx.x;
  float s = 0.f;
  for (int a = 0; a < A; ++a) s += Wp[a] * Wenc[(size_t)a * E_ENC + e];
  wv[e] = s;
  if (blockIdx.x == 0) {
    int t = threadIdx.x;
    float v = Wp[t] * benc[t] + Wp[t + 256] * benc[t + 256];
    red[t] = v;
    __syncthreads();
    for (int off = 128; off > 0; off >>= 1) {
      if (t < off) red[t] += red[t + off];
      __syncthreads();
    }
    if (t == 0) c0[0] = red[0];
  }
}

// ---------------------------------------------------------------------------
// Per-b: enc_mean (bf16), fscore -> softmax over t -> ctx (bf16)
__global__ void k_mean_ctx(const float* __restrict__ features, const float* __restrict__ wv,
                           const float* __restrict__ c0, unsigned short* __restrict__ enc_meanb,
                           unsigned short* __restrict__ ctxb) {
  int b = blockIdx.x, tid = threadIdx.x;
  const float* fb = features + (size_t)b * T * E_ENC;
  __shared__ float s_attw[T];

  float m0 = 0, m1 = 0, m2 = 0, m3 = 0;
  for (int t = 0; t < T; ++t) {
    const float* r = fb + t * E_ENC;
    m0 += r[tid]; m1 += r[tid + 256]; m2 += r[tid + 512]; m3 += r[tid + 768];
  }
  size_t eb = (size_t)b * E_ENC;
  enc_meanb[eb + tid]       = f2bf(m0 * (1.f / 64.f));
  enc_meanb[eb + tid + 256] = f2bf(m1 * (1.f / 64.f));
  enc_meanb[eb + tid + 512] = f2bf(m2 * (1.f / 64.f));
  enc_meanb[eb + tid + 768] = f2bf(m3 * (1.f / 64.f));

  {
    int t = tid >> 2, part = tid & 3;
    const float* r = fb + t * E_ENC + part * 256;
    const float* wp = wv + part * 256;
    float s = 0.f;
    for (int e = 0; e < 256; e += 4) {
      float4 f4 = *(const float4*)(r + e);
      float4 w4 = *(const float4*)(wp + e);
      s += f4.x * w4.x + f4.y * w4.y + f4.z * w4.z + f4.w * w4.w;
    }
    s += __shfl_xor(s, 1);
    s += __shfl_xor(s, 2);
    if (part == 0) s_attw[t] = s + c0[0];
  }
  __syncthreads();
  if (tid < 64) {
    float v = s_attw[tid];
    float mx = v;
    #pragma unroll
    for (int off = 32; off > 0; off >>= 1) mx = fmaxf(mx, __shfl_xor(mx, off));
    float e = expf(v - mx);
    float sm = e;
    #pragma unroll
    for (int off = 32; off > 0; off >>= 1) sm += __shfl_xor(sm, off);
    s_attw[tid] = e / sm;
  }
  __syncthreads();
  float ca = 0, cb = 0, cc = 0, cd = 0;
  for (int t = 0; t < T; ++t) {
    float w = s_attw[t];
    const float* r = fb + t * E_ENC;
    ca += w * r[tid]; cb += w * r[tid + 256]; cc += w * r[tid + 512]; cd += w * r[tid + 768];
  }
  ctxb[eb + tid]       = f2bf(ca);
  ctxb[eb + tid + 256] = f2bf(cb);
  ctxb[eb + tid + 512] = f2bf(cc);
  ctxb[eb + tid + 768] = f2bf(cd);
}

// ---------------------------------------------------------------------------
// Gather embedding rows per caption token -> bf16 Xe[2048][512]
__global__ void k_gather_emb(const float* __restrict__ embed_W,
                             const int* __restrict__ captions,
                             unsigned short* __restrict__ Xe) {
  int g = blockIdx.x, tid = threadIdx.x;
  int cap = captions[g];
  const float* src = embed_W + (size_t)cap * EMB;
  float2 v = *(const float2*)(src + tid * 2);
  unsigned int pk = (unsigned int)f2bf(v.x) | ((unsigned int)f2bf(v.y) << 16);
  *(unsigned int*)(Xe + (size_t)g * EMB + tid * 2) = pk;
}

// Full W1 conversion: w1b[d][k] = bf16(W1[d][k]), k = 0..1535 ([enc|emb] order)
__global__ void k_cvt_w1(const float* __restrict__ W1, unsigned short* __restrict__ w1b) {
  int d = blockIdx.x, tid = threadIdx.x;
  #pragma unroll
  for (int i = 0; i < 3; ++i) {
    int c = tid * 2 + i * 512;
    float2 v = *(const float2*)(W1 + (size_t)d * (E_ENC + EMB) + c);
    unsigned int pk = (unsigned int)f2bf(v.x) | ((unsigned int)f2bf(v.y) << 16);
    *(unsigned int*)(w1b + (size_t)d * (E_ENC + EMB) + c) = pk;
  }
}

// ---------------------------------------------------------------------------
// Fused x1 GEMM: x1[g][d] = b1[d] + [enc_mean(b)||emb(g)] . w1b[d,:]
// M=2048, N=512, K=1536. 64x64 tile, BK=64, XOR slot swizzle. First 16 kt read
// the per-b enc_mean row (constant across the 32 l's of a b); last 8 read Xe.
__global__ __launch_bounds__(256) void k_x1f_mfma(
    const unsigned short* __restrict__ enc_meanb,  // [64][1024] bf16
    const unsigned short* __restrict__ Xe,         // [2048][512] bf16
    const unsigned short* __restrict__ w1b,        // [512][1536] bf16
    const float* __restrict__ b1, float* __restrict__ x1) {
  __shared__ __align__(16) unsigned short As[64 * 64];  // 8 KB
  __shared__ __align__(16) unsigned short Bs[64 * 64];  // 8 KB
  int c0 = blockIdx.x * 64, g0 = blockIdx.y * 64;
  int tid = threadIdx.x, lane = tid & 63, wave = tid >> 6;
  int wr = wave >> 1, wc = wave & 1;
  int rsel = lane & 15, hi = lane >> 4;

  f32x4 acc[2][2];
  #pragma unroll
  for (int m = 0; m < 2; ++m)
    #pragma unroll
    for (int n = 0; n < 2; ++n) acc[m][n] = (f32x4){0.f, 0.f, 0.f, 0.f};

  int r1 = tid >> 3, s1 = tid & 7;
  int sw = (s1 ^ (r1 & 7)) * 8;
  // A sources: rows 0..31 are b=2*by, rows 32..63 are b=2*by+1 (g0 mult of 64)
  const unsigned short* emA1 = enc_meanb + (size_t)(g0 >> 5) * 1024 + sw;
  const unsigned short* emA2 = enc_meanb + (size_t)((g0 >> 5) + 1) * 1024 + sw;
  const unsigned short* xeA1 = Xe + (size_t)(g0 + r1) * 512 + sw;
  const unsigned short* xeA2 = Xe + (size_t)(g0 + r1 + 32) * 512 + sw;
  const unsigned short* gB1 = w1b + (size_t)(c0 + r1) * (E_ENC + EMB) + sw;
  const unsigned short* gB2 = w1b + (size_t)(c0 + r1 + 32) * (E_ENC + EMB) + sw;
  unsigned short* aD1 = As + wave * 512;
  unsigned short* aD2 = As + 2048 + wave * 512;
  unsigned short* bD1 = Bs + wave * 512;
  unsigned short* bD2 = Bs + 2048 + wave * 512;

  int slot0 = hi ^ (rsel & 7);
  int slot1 = (4 + hi) ^ (rsel & 7);

  for (int kt = 0; kt < 24; ++kt) {
    const unsigned short *pA1, *pA2;
    if (kt < 16) { pA1 = emA1 + kt * 64; pA2 = emA2 + kt * 64; }
    else         { pA1 = xeA1 + (kt - 16) * 64; pA2 = xeA2 + (kt - 16) * 64; }
    gload_lds16(pA1, aD1);
    gload_lds16(pA2, aD2);
    gload_lds16(gB1, bD1);
    gload_lds16(gB2, bD2);
    gB1 += 64; gB2 += 64;
    __syncthreads();

    bf16x8 af[2][2], bfr[2][2];
    #pragma unroll
    for (int m = 0; m < 2; ++m) {
      int rowA = (wr * 32 + m * 16 + rsel) * 64;
      af[m][0] = *(const bf16x8*)(As + rowA + slot0 * 8);
      af[m][1] = *(const bf16x8*)(As + rowA + slot1 * 8);
    }
    #pragma unroll
    for (int n = 0; n < 2; ++n) {
      int rowB = (wc * 32 + n * 16 + rsel) * 64;
      bfr[n][0] = *(const bf16x8*)(Bs + rowB + slot0 * 8);
      bfr[n][1] = *(const bf16x8*)(Bs + rowB + slot1 * 8);
    }
    #pragma unroll
    for (int m = 0; m < 2; ++m)
      #pragma unroll
      for (int n = 0; n < 2; ++n) {
        acc[m][n] = __builtin_amdgcn_mfma_f32_16x16x32_bf16(af[m][0], bfr[n][0], acc[m][n], 0, 0, 0);
        acc[m][n] = __builtin_amdgcn_mfma_f32_16x16x32_bf16(af[m][1], bfr[n][1], acc[m][n], 0, 0, 0);
      }
    __syncthreads();
  }

  float bvv[2];
  #pragma unroll
  for (int n = 0; n < 2; ++n) bvv[n] = b1[c0 + wc * 32 + n * 16 + rsel];
  #pragma unroll
  for (int m = 0; m < 2; ++m)
    #pragma unroll
    for (int i = 0; i < 4; ++i) {
      int g = g0 + wr * 32 + m * 16 + hi * 4 + i;
      float* xr = x1 + (size_t)g * D;
      #pragma unroll
      for (int n = 0; n < 2; ++n) {
        int c = c0 + wc * 32 + n * 16 + rsel;
        xr[c] = acc[m][n][i] + bvv[n];
      }
    }
}

// ---------------------------------------------------------------------------
// im2col: Xc[g][k*512+dp] = (l+k-6 >= 0) ? x[b][l+k-6][dp] : 0   (bf16)
__global__ void k_im2col(const float* __restrict__ x, unsigned short* __restrict__ Xc) {
  int g = blockIdx.x, tid = threadIdx.x;
  int b = g >> 5, l = g & 31;
  unsigned short* row = Xc + (size_t)g * KC;
  const float* xb = x + (size_t)b * L * D;
  int d = tid * 2;
  #pragma unroll
  for (int k = 0; k < KSZ; ++k) {
    int lp = l + k - 6;
    unsigned int pk = 0;
    if (lp >= 0) {
      float2 v = *(const float2*)(xb + (size_t)lp * D + d);
      pk = (unsigned int)f2bf(v.x) | ((unsigned int)f2bf(v.y) << 16);
    }
    *(unsigned int*)(row + k * 512 + d) = pk;
  }
}

// ---------------------------------------------------------------------------
// conv weight reorder+convert: wb[c][k*512+dp] = bf16(w[c][dp*7+k])
__global__ void k_cvt_wconv(const float* __restrict__ w, unsigned short* __restrict__ wb) {
  __shared__ float row[KC];  // 14 KiB
  int c = blockIdx.x, tid = threadIdx.x;
  const float* wr = w + (size_t)c * KC;
  for (int i = tid; i < KC; i += 256) row[i] = wr[i];
  __syncthreads();
  unsigned short* ob = wb + (size_t)c * KC;
  int dp = tid * 2;
  #pragma unroll
  for (int k = 0; k < KSZ; ++k) {
    unsigned int pk = (unsigned int)f2bf(row[dp * 7 + k]) |
                      ((unsigned int)f2bf(row[(dp + 1) * 7 + k]) << 16);
    *(unsigned int*)(ob + k * 512 + dp) = pk;
  }
}

// ---------------------------------------------------------------------------
// Conv GEMM: y[g][c] = bias[c] + Xc[g,:] . wb[c,:]   M=2048, N=1024, K=3584
// 64x64 tile, 512 blocks, XOR slot swizzle, 2-phase LDS double-buffer (32 KB).
__global__ __launch_bounds__(256) void k_conv_mfma(
    const unsigned short* __restrict__ Xc, const unsigned short* __restrict__ wb,
    const float* __restrict__ bias, float* __restrict__ y) {
  __shared__ __align__(16) unsigned short As[2][64 * 64];  // 16 KB
  __shared__ __align__(16) unsigned short Bs[2][64 * 64];  // 16 KB
  int c0 = blockIdx.x * 64, g0 = blockIdx.y * 64;
  int tid = threadIdx.x, lane = tid & 63, wave = tid >> 6;
  int wr = wave >> 1, wc = wave & 1;
  int rsel = lane & 15, hi = lane >> 4;

  f32x4 acc[2][2];
  #pragma unroll
  for (int m = 0; m < 2; ++m)
    #pragma unroll
    for (int n = 0; n < 2; ++n) acc[m][n] = (f32x4){0.f, 0.f, 0.f, 0.f};

  int r1 = tid >> 3, s1 = tid & 7;
  int sw = (s1 ^ (r1 & 7)) * 8;              // swizzled global k-segment (shorts)
  const unsigned short* gA1 = Xc + (size_t)(g0 + r1) * KC + sw;
  const unsigned short* gA2 = Xc + (size_t)(g0 + r1 + 32) * KC + sw;
  const unsigned short* gB1 = wb + (size_t)(c0 + r1) * KC + sw;
  const unsigned short* gB2 = wb + (size_t)(c0 + r1 + 32) * KC + sw;

  int slot0 = hi ^ (rsel & 7);        // kk=0
  int slot1 = (4 + hi) ^ (rsel & 7);  // kk=1

  // prologue: stage kt=0 into buf 0
  gload_lds16(gA1, &As[0][wave * 512]);
  gload_lds16(gA2, &As[0][2048 + wave * 512]);
  gload_lds16(gB1, &Bs[0][wave * 512]);
  gload_lds16(gB2, &Bs[0][2048 + wave * 512]);
  gA1 += 64; gA2 += 64; gB1 += 64; gB2 += 64;
  __syncthreads();

  int cur = 0;
  for (int kt = 0; kt < KC / 64; ++kt) {
    if (kt + 1 < KC / 64) {
      int nb = cur ^ 1;
      gload_lds16(gA1, &As[nb][wave * 512]);
      gload_lds16(gA2, &As[nb][2048 + wave * 512]);
      gload_lds16(gB1, &Bs[nb][wave * 512]);
      gload_lds16(gB2, &Bs[nb][2048 + wave * 512]);
      gA1 += 64; gA2 += 64; gB1 += 64; gB2 += 64;
    }

    bf16x8 af[2][2], bfr[2][2];
    #pragma unroll
    for (int m = 0; m < 2; ++m) {
      int rowA = (wr * 32 + m * 16 + rsel) * 64;
      af[m][0] = *(const bf16x8*)(&As[cur][rowA + slot0 * 8]);
      af[m][1] = *(const bf16x8*)(&As[cur][rowA + slot1 * 8]);
    }
    #pragma unroll
    for (int n = 0; n < 2; ++n) {
      int rowB = (wc * 32 + n * 16 + rsel) * 64;
      bfr[n][0] = *(const bf16x8*)(&Bs[cur][rowB + slot0 * 8]);
      bfr[n][1] = *(const bf16x8*)(&Bs[cur][rowB + slot1 * 8]);
    }
    #pragma unroll
    for (int m = 0; m < 2; ++m)
      #pragma unroll
      for (int n = 0; n < 2; ++n) {
        acc[m][n] = __builtin_amdgcn_mfma_f32_16x16x32_bf16(af[m][0], bfr[n][0], acc[m][n], 0, 0, 0);
        acc[m][n] = __builtin_amdgcn_mfma_f32_16x16x32_bf16(af[m][1], bfr[n][1], acc[m][n], 0, 0, 0);
      }
    __syncthreads();   // drains the t+1 stage (vmcnt 0) + protects buf reuse
    cur ^= 1;
  }

  float bv[2];
  #pragma unroll
  for (int n = 0; n < 2; ++n) bv[n] = bias[c0 + wc * 32 + n * 16 + rsel];
  #pragma unroll
  for (int m = 0; m < 2; ++m)
    #pragma unroll
    for (int i = 0; i < 4; ++i) {
      int g = g0 + wr * 32 + m * 16 + hi * 4 + i;
      float* yr = y + (size_t)g * 1024;
      #pragma unroll
      for (int n = 0; n < 2; ++n)
        yr[c0 + wc * 32 + n * 16 + rsel] = acc[m][n][i] + bv[n];
    }
}

// ---------------------------------------------------------------------------
// GLU: xout[g][d] = y[g][d] * sigmoid(y[g][d+512]) + xres[g][d]
__global__ void k_glu(const float* __restrict__ y, const float* __restrict__ xres,
                      float* __restrict__ xout) {
  int idx = blockIdx.x * 256 + threadIdx.x;  // 2048*128
  int g = idx >> 7, d4 = (idx & 127) << 2;
  const float* yr = y + (size_t)g * 1024;
  float4 a = *(const float4*)(yr + d4);
  float4 bq = *(const float4*)(yr + 512 + d4);
  float4 xr = *(const float4*)(xres + (size_t)g * 512 + d4);
  float4 o;
  o.x = a.x / (1.f + expf(-bq.x)) + xr.x;
  o.y = a.y / (1.f + expf(-bq.y)) + xr.y;
  o.z = a.z / (1.f + expf(-bq.z)) + xr.z;
  o.w = a.w / (1.f + expf(-bq.w)) + xr.w;
  *(float4*)(xout + (size_t)g * 512 + d4) = o;
}

// Layer-2 GLU: writes bf16 x3 directly.
__global__ void k_glu_bf16(const float* __restrict__ y, const float* __restrict__ xres,
                           unsigned short* __restrict__ xout) {
  int idx = blockIdx.x * 256 + threadIdx.x;
  int g = idx >> 7, d4 = (idx & 127) << 2;
  const float* yr = y + (size_t)g * 1024;
  float4 a = *(const float4*)(yr + d4);
  float4 bq = *(const float4*)(yr + 512 + d4);
  float4 xr = *(const float4*)(xres + (size_t)g * 512 + d4);
  ushort4 o;
  o.x = f2bf(a.x / (1.f + expf(-bq.x)) + xr.x);
  o.y = f2bf(a.y / (1.f + expf(-bq.y)) + xr.y);
  o.z = f2bf(a.z / (1.f + expf(-bq.z)) + xr.z);
  o.w = f2bf(a.w / (1.f + expf(-bq.w)) + xr.w);
  *(ushort4*)(xout + (size_t)g * 512 + d4) = o;
}

// ---------------------------------------------------------------------------
// cbase[b,v] = b2[v] + ctx[b,:1024] . W2[v,:1024]  as bf16 MFMA.
__global__ __launch_bounds__(256) void k_cbase_mfma(
    const unsigned short* __restrict__ ctxb,  // [64][1024] bf16
    const float* __restrict__ W2,             // [30000][1536] fp32
    const float* __restrict__ b2, float* __restrict__ cbase) {
  __shared__ __align__(16) unsigned short As[64 * 64];    // 8 KB
  __shared__ __align__(16) unsigned short Bs[128 * 64];   // 16 KB
  int v0 = blockIdx.x * 128;
  int tid = threadIdx.x, lane = tid & 63, wave = tid >> 6;
  int rsel = lane & 15, hi = lane >> 4;
  int wc = wave;

  f32x4 acc[4][2];
  #pragma unroll
  for (int m = 0; m < 4; ++m)
    #pragma unroll
    for (int n = 0; n < 2; ++n) acc[m][n] = (f32x4){0.f, 0.f, 0.f, 0.f};

  int ra1 = tid >> 3, sa = tid & 7;
  int ra2 = ra1 + 32;
  const unsigned short* gA1 = ctxb + (size_t)ra1 * 1024 + (sa ^ (ra1 & 7)) * 8;
  const unsigned short* gA2 = ctxb + (size_t)ra2 * 1024 + (sa ^ (ra2 & 7)) * 8;
  unsigned short* aD1 = As + wave * 512;
  unsigned short* aD2 = As + 2048 + wave * 512;

  const float* gB[4];
  int bofs[4];
  #pragma unroll
  for (int p = 0; p < 4; ++p) {
    int row = p * 32 + (tid >> 3);
    int seg = tid & 7;
    int vr = v0 + row; if (vr > V - 1) vr = V - 1;
    gB[p] = W2 + (size_t)vr * (E_ENC + D) + seg * 8;
    bofs[p] = row * 64 + (seg ^ (row & 7)) * 8;
  }

  for (int kt = 0; kt < 16; ++kt) {
    gload_lds16(gA1, aD1);
    gload_lds16(gA2, aD2);
    gA1 += 64; gA2 += 64;
    #pragma unroll
    for (int p = 0; p < 4; ++p) {
      float4 f0 = *(const float4*)(gB[p]);
      float4 f1 = *(const float4*)(gB[p] + 4);
      gB[p] += 64;
      bf16x8 o;
      o[0] = (short)f2bf(f0.x); o[1] = (short)f2bf(f0.y);
      o[2] = (short)f2bf(f0.z); o[3] = (short)f2bf(f0.w);
      o[4] = (short)f2bf(f1.x); o[5] = (short)f2bf(f1.y);
      o[6] = (short)f2bf(f1.z); o[7] = (short)f2bf(f1.w);
      *(bf16x8*)(Bs + bofs[p]) = o;
    }
    __syncthreads();

    bf16x8 af[4][2], bfr[2][2];
    #pragma unroll
    for (int m = 0; m < 4; ++m) {
      int rowA = (m * 16 + rsel) * 64;
      #pragma unroll
      for (int kk = 0; kk < 2; ++kk)
        af[m][kk] = *(const bf16x8*)(As + rowA + ((kk * 4 + hi) ^ (rsel & 7)) * 8);
    }
    #pragma unroll
    for (int n = 0; n < 2; ++n) {
      int rowB = (wc * 32 + n * 16 + rsel) * 64;
      #pragma unroll
      for (int kk = 0; kk < 2; ++kk)
        bfr[n][kk] = *(const bf16x8*)(Bs + rowB + ((kk * 4 + hi) ^ (rsel & 7)) * 8);
    }
    #pragma unroll
    for (int kk = 0; kk < 2; ++kk)
      #pragma unroll
      for (int m = 0; m < 4; ++m)
        #pragma unroll
        for (int n = 0; n < 2; ++n)
          acc[m][n] = __builtin_amdgcn_mfma_f32_16x16x32_bf16(af[m][kk], bfr[n][kk], acc[m][n], 0, 0, 0);
    __syncthreads();
  }

  #pragma unroll
  for (int n = 0; n < 2; ++n) {
    int v = v0 + wc * 32 + n * 16 + rsel;
    if (v >= V) continue;
    float bias = b2[v];
    #pragma unroll
    for (int m = 0; m < 4; ++m)
      #pragma unroll
      for (int i = 0; i < 4; ++i) {
        int b = m * 16 + hi * 4 + i;
        cbase[(size_t)b * V + v] = acc[m][n][i] + bias;
      }
  }
}

// ---------------------------------------------------------------------------
// W2 decode-half conversion: y[v][c] = bf16(W2[v][1024+c])
__global__ void k_cvt_w2d(const float* __restrict__ W2, unsigned short* __restrict__ y) {
  int i = blockIdx.x * 256 + threadIdx.x;   // 30000*128 groups of 4
  int row = i >> 7, c = (i & 127) << 2;
  float4 f = *(const float4*)(W2 + (size_t)row * (E_ENC + D) + E_ENC + c);
  ushort4 o;
  o.x = f2bf(f.x); o.y = f2bf(f.y); o.z = f2bf(f.z); o.w = f2bf(f.w);
  *(ushort4*)(y + (size_t)row * D + c) = o;
}

// ---------------------------------------------------------------------------
// logits[b,s,v] = cbase[b,v] + x3[b,s,:] . W2d[v,:]
// R5 geometry (BK=32, 2D grid v-fastest) + 4-slot XOR swizzle (free 2-way
// bank spread: phys_slot = hi ^ ((row>>1)&3)) + 2-phase dbuf at 32 KB LDS.
__global__ __launch_bounds__(256) void k_logits_mfma(
    const unsigned short* __restrict__ Ab,   // x3 bf16 [2048][512]
    const unsigned short* __restrict__ Bb,   // W2d bf16 [30000][512]
    const float* __restrict__ cbase, float* __restrict__ out) {
  __shared__ __align__(16) unsigned short As[2][128 * 32];  // 16 KB
  __shared__ __align__(16) unsigned short Bs[2][128 * 32];  // 16 KB
  int v0 = blockIdx.x * 128, g0 = blockIdx.y * 128;
  int tid = threadIdx.x, lane = tid & 63, wave = tid >> 6;
  int wr = wave >> 1, wc = wave & 1;
  int rsel = lane & 15, hi = lane >> 4;

  f32x4 acc[4][4];
  #pragma unroll
  for (int m = 0; m < 4; ++m)
    #pragma unroll
    for (int n = 0; n < 4; ++n) acc[m][n] = (f32x4){0.f, 0.f, 0.f, 0.f};

  // staging: 512 16B chunks per matrix per step; chunk c: row c>>2, phys slot c&3
  // global segment = phys_slot ^ ((row>>1)&3); same swizzle value for row+64.
  int r1 = tid >> 2, s1 = tid & 3;
  int seg = (s1 ^ ((r1 >> 1) & 3)) * 8;
  const unsigned short* gA1 = Ab + (size_t)(g0 + r1) * 512 + seg;
  const unsigned short* gA2 = Ab + (size_t)(g0 + r1 + 64) * 512 + seg;
  int vr1 = v0 + r1;      if (vr1 > V - 1) vr1 = V - 1;
  int vr2 = v0 + r1 + 64; if (vr2 > V - 1) vr2 = V - 1;
  const unsigned short* gB1 = Bb + (size_t)vr1 * 512 + seg;
  const unsigned short* gB2 = Bb + (size_t)vr2 * 512 + seg;

  // prologue: stage kt=0 into buf 0
  gload_lds16(gA1, &As[0][wave * 512]);
  gload_lds16(gA2, &As[0][2048 + wave * 512]);
  gload_lds16(gB1, &Bs[0][wave * 512]);
  gload_lds16(gB2, &Bs[0][2048 + wave * 512]);
  gA1 += 32; gA2 += 32; gB1 += 32; gB2 += 32;
  __syncthreads();

  int sl = (rsel >> 1) & 3;   // read-side swizzle term (rows are base+rsel, base%16==0)
  int cur = 0;
  for (int kt = 0; kt < 16; ++kt) {
    if (kt + 1 < 16) {
      int nb = cur ^ 1;
      gload_lds16(gA1, &As[nb][wave * 512]);
      gload_lds16(gA2, &As[nb][2048 + wave * 512]);
      gload_lds16(gB1, &Bs[nb][wave * 512]);
      gload_lds16(gB2, &Bs[nb][2048 + wave * 512]);
      gA1 += 32; gA2 += 32; gB1 += 32; gB2 += 32;
    }

    bf16x8 af[4], bfr[4];
    #pragma unroll
    for (int m = 0; m < 4; ++m)
      af[m] = *(const bf16x8*)(&As[cur][(wr * 64 + m * 16 + rsel) * 32 + ((hi ^ sl) * 8)]);
    #pragma unroll
    for (int n = 0; n < 4; ++n)
      bfr[n] = *(const bf16x8*)(&Bs[cur][(wc * 64 + n * 16 + rsel) * 32 + ((hi ^ sl) * 8)]);
    #pragma unroll
    for (int m = 0; m < 4; ++m)
      #pragma unroll
      for (int n = 0; n < 4; ++n)
        acc[m][n] = __builtin_amdgcn_mfma_f32_16x16x32_bf16(af[m], bfr[n], acc[m][n], 0, 0, 0);
    __syncthreads();   // drains t+1 stage + protects buffer reuse
    cur ^= 1;
  }

  #pragma unroll
  for (int m = 0; m < 4; ++m) {
    #pragma unroll
    for (int i = 0; i < 4; ++i) {
      int g = g0 + wr * 64 + m * 16 + hi * 4 + i;
      int b = g >> 5, lt = g & 31;
      if (lt >= S) continue;
      size_t orow = ((size_t)b * S + lt) * V;
      const float* cb = cbase + (size_t)b * V;
      #pragma unroll
      for (int n = 0; n < 4; ++n) {
        int v = v0 + wc * 64 + n * 16 + rsel;
        if (v < V) out[orow + v] = acc[m][n][i] + cb[v];
      }
    }
  }
}

// ---------------------------------------------------------------------------
extern "C" void kernel_launch(void* const* d_in, const int* in_sizes, int n_in,
                              void* d_out, int out_size, void* d_ws, size_t ws_size,
                              hipStream_t stream) {
  const float* features = (const float*)d_in[0];
  const int*   captions = (const int*)d_in[1];
  const float* embed_W  = (const float*)d_in[3];
  const float* W1   = (const float*)d_in[4];
  const float* b1   = (const float*)d_in[5];
  const float* cw1  = (const float*)d_in[6];
  const float* cb1  = (const float*)d_in[7];
  const float* cw2  = (const float*)d_in[8];
  const float* cb2  = (const float*)d_in[9];
  const float* Wenc = (const float*)d_in[10];
  const float* benc = (const float*)d_in[11];
  const float* Wp   = (const float*)d_in[14];
  const float* W2   = (const float*)d_in[16];
  const float* b2   = (const float*)d_in[17];
  float* out = (float*)d_out;

  float* ws = (float*)d_ws;
  float* wv       = ws;                 // 1024
  float* c0       = ws + 1024;          // 16
  unsigned short* enc_meanb = (unsigned short*)(ws + 1040);  // 65536 bf16
  unsigned short* ctxb = (unsigned short*)(ws + 66576);      // 65536 bf16
  // ws+132112 .. : old base1 slot (unused)
  float* xA       = ws + 164880;        // 1048576 (x1; dead after GLU1)
  float* xB       = ws + 1213456;       // 1048576 (x2)
  float* y        = ws + 2262032;       // 2097152 (conv GEMM out; cbase aliases)
  float* cbase    = y;                  // 1920000 <= 2097152
  unsigned short* x3b  = (unsigned short*)xA;             // 1048576 bf16 (xA dead)
  unsigned short* Xc   = (unsigned short*)(ws + 4359184); // 7340032 bf16
  unsigned short* wbuf = (unsigned short*)(ws + 8029200); // 3670016 bf16
  unsigned short* W2d  = (unsigned short*)(ws + 9864208); // 15360000 bf16
  // Xe / w1b live inside the Xc region (free until im2col layer 1)
  unsigned short* Xe  = Xc;                  // 1048576 bf16
  unsigned short* w1b = Xc + 1048576;        // 786432 bf16 (full W1)
  // end: 17,544,208 floats = 70.2 MB (unchanged)

  hipLaunchKernelGGL(k_cvt_w2d,  dim3(15000),   dim3(256), 0, stream, W2, W2d);
  hipLaunchKernelGGL(k_wv,       dim3(4),       dim3(256), 0, stream, Wenc, Wp, benc, wv, c0);
  hipLaunchKernelGGL(k_mean_ctx, dim3(B),       dim3(256), 0, stream, features, wv, c0, enc_meanb, ctxb);

  // x1 = b1 + [enc_mean||emb] @ W1ᵀ  (fused MFMA, K=1536; k_base1 eliminated)
  hipLaunchKernelGGL(k_gather_emb, dim3(2048),  dim3(256), 0, stream, embed_W, captions, Xe);
  hipLaunchKernelGGL(k_cvt_w1,     dim3(512),   dim3(256), 0, stream, W1, w1b);
  hipLaunchKernelGGL(k_x1f_mfma,   dim3(8, 32), dim3(256), 0, stream, enc_meanb, Xe, w1b, b1, xA);

  // conv layer 1
  hipLaunchKernelGGL(k_cvt_wconv, dim3(1024),   dim3(256), 0, stream, cw1, wbuf);
  hipLaunchKernelGGL(k_im2col,    dim3(2048),   dim3(256), 0, stream, xA, Xc);
  hipLaunchKernelGGL(k_conv_mfma, dim3(16, 32), dim3(256), 0, stream, Xc, wbuf, cb1, y);
  hipLaunchKernelGGL(k_glu,       dim3(1024),   dim3(256), 0, stream, y, xA, xB);

  // conv layer 2
  hipLaunchKernelGGL(k_cvt_wconv, dim3(1024),   dim3(256), 0, stream, cw2, wbuf);
  hipLaunchKernelGGL(k_im2col,    dim3(2048),   dim3(256), 0, stream, xB, Xc);
  hipLaunchKernelGGL(k_conv_mfma, dim3(16, 32), dim3(256), 0, stream, Xc, wbuf, cb2, y);
  hipLaunchKernelGGL(k_glu_bf16,  dim3(1024),   dim3(256), 0, stream, y, xB, x3b);

  hipLaunchKernelGGL(k_cbase_mfma, dim3(235),   dim3(256), 0, stream, ctxb, W2, b2, cbase);
  hipLaunchKernelGGL(k_logits_mfma, dim3(235, 16), dim3(256), 0, stream, x3b, W2d, cbase, out);
}

// Round 9
// 407.424 us; speedup vs baseline: 1.2848x; 1.0430x over previous
//
#include <hip/hip_runtime.h>
#include <hip/hip_bf16.h>
#include <math.h>

// Sizes (fixed by the problem)
#define B 64
#define T 64
#define E_ENC 1024
#define EMB 512
#define D 512
#define L 32
#define S 31
#define A 512
#define V 30000
#define KSZ 7
#define KC (D * KSZ)   // 3584 = conv GEMM K

typedef __attribute__((ext_vector_type(8))) short bf16x8;
typedef __attribute__((ext_vector_type(4))) float f32x4;

__device__ __forceinline__ unsigned short f2bf(float f) {
  union { float f; unsigned int u; } x; x.f = f;
  unsigned int r = (x.u + 0x7fffu + ((x.u >> 16) & 1u)) >> 16;
  return (unsigned short)r;
}

__device__ __forceinline__ void gload_lds16(const void* g, void* l) {
  __builtin_amdgcn_global_load_lds(
      (const __attribute__((address_space(1))) unsigned int*)g,
      (__attribute__((address_space(3))) unsigned int*)l, 16, 0, 0);
}

// ---------------------------------------------------------------------------
// wv[e] = sum_a Wp[a]*Wenc[a,e];  c0 = sum_a benc[a]*Wp[a]
__global__ void k_wv(const float* __restrict__ Wenc, const float* __restrict__ Wp,
                     const float* __restrict__ benc, float* __restrict__ wv,
                     float* __restrict__ c0) {
  __shared__ float red[256];
  int e = blockIdx.x * 256 + threadIdx.x;
  float s = 0.f;
  for (int a = 0; a < A; ++a) s += Wp[a] * Wenc[(size_t)a * E_ENC + e];
  wv[e] = s;
  if (blockIdx.x == 0) {
    int t = threadIdx.x;
    float v = Wp[t] * benc[t] + Wp[t + 256] * benc[t + 256];
    red[t] = v;
    __syncthreads();
    for (int off = 128; off > 0; off >>= 1) {
      if (t < off) red[t] += red[t + off];
      __syncthreads();
    }
    if (t == 0) c0[0] = red[0];
  }
}

// ---------------------------------------------------------------------------
// Per-b: enc_mean (bf16), fscore -> softmax over t -> ctx (bf16)
__global__ void k_mean_ctx(const float* __restrict__ features, const float* __restrict__ wv,
                           const float* __restrict__ c0, unsigned short* __restrict__ enc_meanb,
                           unsigned short* __restrict__ ctxb) {
  int b = blockIdx.x, tid = threadIdx.x;
  const float* fb = features + (size_t)b * T * E_ENC;
  __shared__ float s_attw[T];

  float m0 = 0, m1 = 0, m2 = 0, m3 = 0;
  for (int t = 0; t < T; ++t) {
    const float* r = fb + t * E_ENC;
    m0 += r[tid]; m1 += r[tid + 256]; m2 += r[tid + 512]; m3 += r[tid + 768];
  }
  size_t eb = (size_t)b * E_ENC;
  enc_meanb[eb + tid]       = f2bf(m0 * (1.f / 64.f));
  enc_meanb[eb + tid + 256] = f2bf(m1 * (1.f / 64.f));
  enc_meanb[eb + tid + 512] = f2bf(m2 * (1.f / 64.f));
  enc_meanb[eb + tid + 768] = f2bf(m3 * (1.f / 64.f));

  {
    int t = tid >> 2, part = tid & 3;
    const float* r = fb + t * E_ENC + part * 256;
    const float* wp = wv + part * 256;
    float s = 0.f;
    for (int e = 0; e < 256; e += 4) {
      float4 f4 = *(const float4*)(r + e);
      float4 w4 = *(const float4*)(wp + e);
      s += f4.x * w4.x + f4.y * w4.y + f4.z * w4.z + f4.w * w4.w;
    }
    s += __shfl_xor(s, 1);
    s += __shfl_xor(s, 2);
    if (part == 0) s_attw[t] = s + c0[0];
  }
  __syncthreads();
  if (tid < 64) {
    float v = s_attw[tid];
    float mx = v;
    #pragma unroll
    for (int off = 32; off > 0; off >>= 1) mx = fmaxf(mx, __shfl_xor(mx, off));
    float e = expf(v - mx);
    float sm = e;
    #pragma unroll
    for (int off = 32; off > 0; off >>= 1) sm += __shfl_xor(sm, off);
    s_attw[tid] = e / sm;
  }
  __syncthreads();
  float ca = 0, cb = 0, cc = 0, cd = 0;
  for (int t = 0; t < T; ++t) {
    float w = s_attw[t];
    const float* r = fb + t * E_ENC;
    ca += w * r[tid]; cb += w * r[tid + 256]; cc += w * r[tid + 512]; cd += w * r[tid + 768];
  }
  ctxb[eb + tid]       = f2bf(ca);
  ctxb[eb + tid + 256] = f2bf(cb);
  ctxb[eb + tid + 512] = f2bf(cc);
  ctxb[eb + tid + 768] = f2bf(cd);
}

// ---------------------------------------------------------------------------
// Gather embedding rows per caption token -> bf16 Xe[2048][512]
__global__ void k_gather_emb(const float* __restrict__ embed_W,
                             const int* __restrict__ captions,
                             unsigned short* __restrict__ Xe) {
  int g = blockIdx.x, tid = threadIdx.x;
  int cap = captions[g];
  const float* src = embed_W + (size_t)cap * EMB;
  float2 v = *(const float2*)(src + tid * 2);
  unsigned int pk = (unsigned int)f2bf(v.x) | ((unsigned int)f2bf(v.y) << 16);
  *(unsigned int*)(Xe + (size_t)g * EMB + tid * 2) = pk;
}

// Full W1 conversion: w1b[d][k] = bf16(W1[d][k]), k = 0..1535 ([enc|emb] order)
__global__ void k_cvt_w1(const float* __restrict__ W1, unsigned short* __restrict__ w1b) {
  int d = blockIdx.x, tid = threadIdx.x;
  #pragma unroll
  for (int i = 0; i < 3; ++i) {
    int c = tid * 2 + i * 512;
    float2 v = *(const float2*)(W1 + (size_t)d * (E_ENC + EMB) + c);
    unsigned int pk = (unsigned int)f2bf(v.x) | ((unsigned int)f2bf(v.y) << 16);
    *(unsigned int*)(w1b + (size_t)d * (E_ENC + EMB) + c) = pk;
  }
}

// ---------------------------------------------------------------------------
// Fused x1 GEMM: x1[g][d] = b1[d] + [enc_mean(b)||emb(g)] . w1b[d,:]
// M=2048, N=512, K=1536. 64x64 tile, BK=64, XOR slot swizzle.
__global__ __launch_bounds__(256) void k_x1f_mfma(
    const unsigned short* __restrict__ enc_meanb,  // [64][1024] bf16
    const unsigned short* __restrict__ Xe,         // [2048][512] bf16
    const unsigned short* __restrict__ w1b,        // [512][1536] bf16
    const float* __restrict__ b1, float* __restrict__ x1) {
  __shared__ __align__(16) unsigned short As[64 * 64];  // 8 KB
  __shared__ __align__(16) unsigned short Bs[64 * 64];  // 8 KB
  int c0 = blockIdx.x * 64, g0 = blockIdx.y * 64;
  int tid = threadIdx.x, lane = tid & 63, wave = tid >> 6;
  int wr = wave >> 1, wc = wave & 1;
  int rsel = lane & 15, hi = lane >> 4;

  f32x4 acc[2][2];
  #pragma unroll
  for (int m = 0; m < 2; ++m)
    #pragma unroll
    for (int n = 0; n < 2; ++n) acc[m][n] = (f32x4){0.f, 0.f, 0.f, 0.f};

  int r1 = tid >> 3, s1 = tid & 7;
  int sw = (s1 ^ (r1 & 7)) * 8;
  const unsigned short* emA1 = enc_meanb + (size_t)(g0 >> 5) * 1024 + sw;
  const unsigned short* emA2 = enc_meanb + (size_t)((g0 >> 5) + 1) * 1024 + sw;
  const unsigned short* xeA1 = Xe + (size_t)(g0 + r1) * 512 + sw;
  const unsigned short* xeA2 = Xe + (size_t)(g0 + r1 + 32) * 512 + sw;
  const unsigned short* gB1 = w1b + (size_t)(c0 + r1) * (E_ENC + EMB) + sw;
  const unsigned short* gB2 = w1b + (size_t)(c0 + r1 + 32) * (E_ENC + EMB) + sw;
  unsigned short* aD1 = As + wave * 512;
  unsigned short* aD2 = As + 2048 + wave * 512;
  unsigned short* bD1 = Bs + wave * 512;
  unsigned short* bD2 = Bs + 2048 + wave * 512;

  int slot0 = hi ^ (rsel & 7);
  int slot1 = (4 + hi) ^ (rsel & 7);

  for (int kt = 0; kt < 24; ++kt) {
    const unsigned short *pA1, *pA2;
    if (kt < 16) { pA1 = emA1 + kt * 64; pA2 = emA2 + kt * 64; }
    else         { pA1 = xeA1 + (kt - 16) * 64; pA2 = xeA2 + (kt - 16) * 64; }
    gload_lds16(pA1, aD1);
    gload_lds16(pA2, aD2);
    gload_lds16(gB1, bD1);
    gload_lds16(gB2, bD2);
    gB1 += 64; gB2 += 64;
    __syncthreads();

    bf16x8 af[2][2], bfr[2][2];
    #pragma unroll
    for (int m = 0; m < 2; ++m) {
      int rowA = (wr * 32 + m * 16 + rsel) * 64;
      af[m][0] = *(const bf16x8*)(As + rowA + slot0 * 8);
      af[m][1] = *(const bf16x8*)(As + rowA + slot1 * 8);
    }
    #pragma unroll
    for (int n = 0; n < 2; ++n) {
      int rowB = (wc * 32 + n * 16 + rsel) * 64;
      bfr[n][0] = *(const bf16x8*)(Bs + rowB + slot0 * 8);
      bfr[n][1] = *(const bf16x8*)(Bs + rowB + slot1 * 8);
    }
    #pragma unroll
    for (int m = 0; m < 2; ++m)
      #pragma unroll
      for (int n = 0; n < 2; ++n) {
        acc[m][n] = __builtin_amdgcn_mfma_f32_16x16x32_bf16(af[m][0], bfr[n][0], acc[m][n], 0, 0, 0);
        acc[m][n] = __builtin_amdgcn_mfma_f32_16x16x32_bf16(af[m][1], bfr[n][1], acc[m][n], 0, 0, 0);
      }
    __syncthreads();
  }

  float bvv[2];
  #pragma unroll
  for (int n = 0; n < 2; ++n) bvv[n] = b1[c0 + wc * 32 + n * 16 + rsel];
  #pragma unroll
  for (int m = 0; m < 2; ++m)
    #pragma unroll
    for (int i = 0; i < 4; ++i) {
      int g = g0 + wr * 32 + m * 16 + hi * 4 + i;
      float* xr = x1 + (size_t)g * D;
      #pragma unroll
      for (int n = 0; n < 2; ++n) {
        int c = c0 + wc * 32 + n * 16 + rsel;
        xr[c] = acc[m][n][i] + bvv[n];
      }
    }
}

// ---------------------------------------------------------------------------
// im2col: Xc[g][k*512+dp] = (l+k-6 >= 0) ? x[b][l+k-6][dp] : 0   (bf16)
__global__ void k_im2col(const float* __restrict__ x, unsigned short* __restrict__ Xc) {
  int g = blockIdx.x, tid = threadIdx.x;
  int b = g >> 5, l = g & 31;
  unsigned short* row = Xc + (size_t)g * KC;
  const float* xb = x + (size_t)b * L * D;
  int d = tid * 2;
  #pragma unroll
  for (int k = 0; k < KSZ; ++k) {
    int lp = l + k - 6;
    unsigned int pk = 0;
    if (lp >= 0) {
      float2 v = *(const float2*)(xb + (size_t)lp * D + d);
      pk = (unsigned int)f2bf(v.x) | ((unsigned int)f2bf(v.y) << 16);
    }
    *(unsigned int*)(row + k * 512 + d) = pk;
  }
}

// ---------------------------------------------------------------------------
// conv weight reorder+convert: wb[c][k*512+dp] = bf16(w[c][dp*7+k])
__global__ void k_cvt_wconv(const float* __restrict__ w, unsigned short* __restrict__ wb) {
  __shared__ float row[KC];  // 14 KiB
  int c = blockIdx.x, tid = threadIdx.x;
  const float* wr = w + (size_t)c * KC;
  for (int i = tid; i < KC; i += 256) row[i] = wr[i];
  __syncthreads();
  unsigned short* ob = wb + (size_t)c * KC;
  int dp = tid * 2;
  #pragma unroll
  for (int k = 0; k < KSZ; ++k) {
    unsigned int pk = (unsigned int)f2bf(row[dp * 7 + k]) |
                      ((unsigned int)f2bf(row[(dp + 1) * 7 + k]) << 16);
    *(unsigned int*)(ob + k * 512 + dp) = pk;
  }
}

// ---------------------------------------------------------------------------
// Conv GEMM: y[g][c] = bias[c] + Xc[g,:] . wb[c,:]   M=2048, N=1024, K=3584
// 64x64 tile, 512 blocks, XOR slot swizzle, 2-phase LDS double-buffer (32 KB).
__global__ __launch_bounds__(256) void k_conv_mfma(
    const unsigned short* __restrict__ Xc, const unsigned short* __restrict__ wb,
    const float* __restrict__ bias, float* __restrict__ y) {
  __shared__ __align__(16) unsigned short As[2][64 * 64];  // 16 KB
  __shared__ __align__(16) unsigned short Bs[2][64 * 64];  // 16 KB
  int c0 = blockIdx.x * 64, g0 = blockIdx.y * 64;
  int tid = threadIdx.x, lane = tid & 63, wave = tid >> 6;
  int wr = wave >> 1, wc = wave & 1;
  int rsel = lane & 15, hi = lane >> 4;

  f32x4 acc[2][2];
  #pragma unroll
  for (int m = 0; m < 2; ++m)
    #pragma unroll
    for (int n = 0; n < 2; ++n) acc[m][n] = (f32x4){0.f, 0.f, 0.f, 0.f};

  int r1 = tid >> 3, s1 = tid & 7;
  int sw = (s1 ^ (r1 & 7)) * 8;              // swizzled global k-segment (shorts)
  const unsigned short* gA1 = Xc + (size_t)(g0 + r1) * KC + sw;
  const unsigned short* gA2 = Xc + (size_t)(g0 + r1 + 32) * KC + sw;
  const unsigned short* gB1 = wb + (size_t)(c0 + r1) * KC + sw;
  const unsigned short* gB2 = wb + (size_t)(c0 + r1 + 32) * KC + sw;

  int slot0 = hi ^ (rsel & 7);        // kk=0
  int slot1 = (4 + hi) ^ (rsel & 7);  // kk=1

  // prologue: stage kt=0 into buf 0
  gload_lds16(gA1, &As[0][wave * 512]);
  gload_lds16(gA2, &As[0][2048 + wave * 512]);
  gload_lds16(gB1, &Bs[0][wave * 512]);
  gload_lds16(gB2, &Bs[0][2048 + wave * 512]);
  gA1 += 64; gA2 += 64; gB1 += 64; gB2 += 64;
  __syncthreads();

  int cur = 0;
  for (int kt = 0; kt < KC / 64; ++kt) {
    if (kt + 1 < KC / 64) {
      int nb = cur ^ 1;
      gload_lds16(gA1, &As[nb][wave * 512]);
      gload_lds16(gA2, &As[nb][2048 + wave * 512]);
      gload_lds16(gB1, &Bs[nb][wave * 512]);
      gload_lds16(gB2, &Bs[nb][2048 + wave * 512]);
      gA1 += 64; gA2 += 64; gB1 += 64; gB2 += 64;
    }

    bf16x8 af[2][2], bfr[2][2];
    #pragma unroll
    for (int m = 0; m < 2; ++m) {
      int rowA = (wr * 32 + m * 16 + rsel) * 64;
      af[m][0] = *(const bf16x8*)(&As[cur][rowA + slot0 * 8]);
      af[m][1] = *(const bf16x8*)(&As[cur][rowA + slot1 * 8]);
    }
    #pragma unroll
    for (int n = 0; n < 2; ++n) {
      int rowB = (wc * 32 + n * 16 + rsel) * 64;
      bfr[n][0] = *(const bf16x8*)(&Bs[cur][rowB + slot0 * 8]);
      bfr[n][1] = *(const bf16x8*)(&Bs[cur][rowB + slot1 * 8]);
    }
    #pragma unroll
    for (int m = 0; m < 2; ++m)
      #pragma unroll
      for (int n = 0; n < 2; ++n) {
        acc[m][n] = __builtin_amdgcn_mfma_f32_16x16x32_bf16(af[m][0], bfr[n][0], acc[m][n], 0, 0, 0);
        acc[m][n] = __builtin_amdgcn_mfma_f32_16x16x32_bf16(af[m][1], bfr[n][1], acc[m][n], 0, 0, 0);
      }
    __syncthreads();   // drains the t+1 stage (vmcnt 0) + protects buf reuse
    cur ^= 1;
  }

  float bv[2];
  #pragma unroll
  for (int n = 0; n < 2; ++n) bv[n] = bias[c0 + wc * 32 + n * 16 + rsel];
  #pragma unroll
  for (int m = 0; m < 2; ++m)
    #pragma unroll
    for (int i = 0; i < 4; ++i) {
      int g = g0 + wr * 32 + m * 16 + hi * 4 + i;
      float* yr = y + (size_t)g * 1024;
      #pragma unroll
      for (int n = 0; n < 2; ++n)
        yr[c0 + wc * 32 + n * 16 + rsel] = acc[m][n][i] + bv[n];
    }
}

// ---------------------------------------------------------------------------
// GLU: xout[g][d] = y[g][d] * sigmoid(y[g][d+512]) + xres[g][d]
__global__ void k_glu(const float* __restrict__ y, const float* __restrict__ xres,
                      float* __restrict__ xout) {
  int idx = blockIdx.x * 256 + threadIdx.x;  // 2048*128
  int g = idx >> 7, d4 = (idx & 127) << 2;
  const float* yr = y + (size_t)g * 1024;
  float4 a = *(const float4*)(yr + d4);
  float4 bq = *(const float4*)(yr + 512 + d4);
  float4 xr = *(const float4*)(xres + (size_t)g * 512 + d4);
  float4 o;
  o.x = a.x / (1.f + expf(-bq.x)) + xr.x;
  o.y = a.y / (1.f + expf(-bq.y)) + xr.y;
  o.z = a.z / (1.f + expf(-bq.z)) + xr.z;
  o.w = a.w / (1.f + expf(-bq.w)) + xr.w;
  *(float4*)(xout + (size_t)g * 512 + d4) = o;
}

// Layer-2 GLU: writes bf16 x3 directly.
__global__ void k_glu_bf16(const float* __restrict__ y, const float* __restrict__ xres,
                           unsigned short* __restrict__ xout) {
  int idx = blockIdx.x * 256 + threadIdx.x;
  int g = idx >> 7, d4 = (idx & 127) << 2;
  const float* yr = y + (size_t)g * 1024;
  float4 a = *(const float4*)(yr + d4);
  float4 bq = *(const float4*)(yr + 512 + d4);
  float4 xr = *(const float4*)(xres + (size_t)g * 512 + d4);
  ushort4 o;
  o.x = f2bf(a.x / (1.f + expf(-bq.x)) + xr.x);
  o.y = f2bf(a.y / (1.f + expf(-bq.y)) + xr.y);
  o.z = f2bf(a.z / (1.f + expf(-bq.z)) + xr.z);
  o.w = f2bf(a.w / (1.f + expf(-bq.w)) + xr.w);
  *(ushort4*)(xout + (size_t)g * 512 + d4) = o;
}

// ---------------------------------------------------------------------------
// cbase[b,v] = b2[v] + ctx[b,:1024] . W2[v,:1024]  as bf16 MFMA.
__global__ __launch_bounds__(256) void k_cbase_mfma(
    const unsigned short* __restrict__ ctxb,  // [64][1024] bf16
    const float* __restrict__ W2,             // [30000][1536] fp32
    const float* __restrict__ b2, float* __restrict__ cbase) {
  __shared__ __align__(16) unsigned short As[64 * 64];    // 8 KB
  __shared__ __align__(16) unsigned short Bs[128 * 64];   // 16 KB
  int v0 = blockIdx.x * 128;
  int tid = threadIdx.x, lane = tid & 63, wave = tid >> 6;
  int rsel = lane & 15, hi = lane >> 4;
  int wc = wave;

  f32x4 acc[4][2];
  #pragma unroll
  for (int m = 0; m < 4; ++m)
    #pragma unroll
    for (int n = 0; n < 2; ++n) acc[m][n] = (f32x4){0.f, 0.f, 0.f, 0.f};

  int ra1 = tid >> 3, sa = tid & 7;
  int ra2 = ra1 + 32;
  const unsigned short* gA1 = ctxb + (size_t)ra1 * 1024 + (sa ^ (ra1 & 7)) * 8;
  const unsigned short* gA2 = ctxb + (size_t)ra2 * 1024 + (sa ^ (ra2 & 7)) * 8;
  unsigned short* aD1 = As + wave * 512;
  unsigned short* aD2 = As + 2048 + wave * 512;

  const float* gB[4];
  int bofs[4];
  #pragma unroll
  for (int p = 0; p < 4; ++p) {
    int row = p * 32 + (tid >> 3);
    int seg = tid & 7;
    int vr = v0 + row; if (vr > V - 1) vr = V - 1;
    gB[p] = W2 + (size_t)vr * (E_ENC + D) + seg * 8;
    bofs[p] = row * 64 + (seg ^ (row & 7)) * 8;
  }

  for (int kt = 0; kt < 16; ++kt) {
    gload_lds16(gA1, aD1);
    gload_lds16(gA2, aD2);
    gA1 += 64; gA2 += 64;
    #pragma unroll
    for (int p = 0; p < 4; ++p) {
      float4 f0 = *(const float4*)(gB[p]);
      float4 f1 = *(const float4*)(gB[p] + 4);
      gB[p] += 64;
      bf16x8 o;
      o[0] = (short)f2bf(f0.x); o[1] = (short)f2bf(f0.y);
      o[2] = (short)f2bf(f0.z); o[3] = (short)f2bf(f0.w);
      o[4] = (short)f2bf(f1.x); o[5] = (short)f2bf(f1.y);
      o[6] = (short)f2bf(f1.z); o[7] = (short)f2bf(f1.w);
      *(bf16x8*)(Bs + bofs[p]) = o;
    }
    __syncthreads();

    bf16x8 af[4][2], bfr[2][2];
    #pragma unroll
    for (int m = 0; m < 4; ++m) {
      int rowA = (m * 16 + rsel) * 64;
      #pragma unroll
      for (int kk = 0; kk < 2; ++kk)
        af[m][kk] = *(const bf16x8*)(As + rowA + ((kk * 4 + hi) ^ (rsel & 7)) * 8);
    }
    #pragma unroll
    for (int n = 0; n < 2; ++n) {
      int rowB = (wc * 32 + n * 16 + rsel) * 64;
      #pragma unroll
      for (int kk = 0; kk < 2; ++kk)
        bfr[n][kk] = *(const bf16x8*)(Bs + rowB + ((kk * 4 + hi) ^ (rsel & 7)) * 8);
    }
    #pragma unroll
    for (int kk = 0; kk < 2; ++kk)
      #pragma unroll
      for (int m = 0; m < 4; ++m)
        #pragma unroll
        for (int n = 0; n < 2; ++n)
          acc[m][n] = __builtin_amdgcn_mfma_f32_16x16x32_bf16(af[m][kk], bfr[n][kk], acc[m][n], 0, 0, 0);
    __syncthreads();
  }

  #pragma unroll
  for (int n = 0; n < 2; ++n) {
    int v = v0 + wc * 32 + n * 16 + rsel;
    if (v >= V) continue;
    float bias = b2[v];
    #pragma unroll
    for (int m = 0; m < 4; ++m)
      #pragma unroll
      for (int i = 0; i < 4; ++i) {
        int b = m * 16 + hi * 4 + i;
        cbase[(size_t)b * V + v] = acc[m][n][i] + bias;
      }
  }
}

// ---------------------------------------------------------------------------
// W2 decode-half conversion: y[v][c] = bf16(W2[v][1024+c])
__global__ void k_cvt_w2d(const float* __restrict__ W2, unsigned short* __restrict__ y) {
  int i = blockIdx.x * 256 + threadIdx.x;   // 30000*128 groups of 4
  int row = i >> 7, c = (i & 127) << 2;
  float4 f = *(const float4*)(W2 + (size_t)row * (E_ENC + D) + E_ENC + c);
  ushort4 o;
  o.x = f2bf(f.x); o.y = f2bf(f.y); o.z = f2bf(f.z); o.w = f2bf(f.w);
  *(ushort4*)(y + (size_t)row * D + c) = o;
}

// ---------------------------------------------------------------------------
// logits[b,s,v] = cbase[b,v] + x3[b,s,:] . W2d[v,:]
// R8 structure (BK=32, 4-slot XOR swizzle, 2-phase dbuf @32KB) + XCD-bijective
// 1D remap: 3760 = 8*470, ord = (flat&7)*470 + flat>>3, g-tile fastest within
// an XCD chunk -> all 16 g-tiles of a v-tile on one XCD (W2d fetched once).
__global__ __launch_bounds__(256) void k_logits_mfma(
    const unsigned short* __restrict__ Ab,   // x3 bf16 [2048][512]
    const unsigned short* __restrict__ Bb,   // W2d bf16 [30000][512]
    const float* __restrict__ cbase, float* __restrict__ out) {
  __shared__ __align__(16) unsigned short As[2][128 * 32];  // 16 KB
  __shared__ __align__(16) unsigned short Bs[2][128 * 32];  // 16 KB
  int flat = blockIdx.x;                  // 3760 = 8 * 470
  int ord = (flat & 7) * 470 + (flat >> 3);
  int v0 = (ord >> 4) * 128, g0 = (ord & 15) * 128;
  int tid = threadIdx.x, lane = tid & 63, wave = tid >> 6;
  int wr = wave >> 1, wc = wave & 1;
  int rsel = lane & 15, hi = lane >> 4;

  f32x4 acc[4][4];
  #pragma unroll
  for (int m = 0; m < 4; ++m)
    #pragma unroll
    for (int n = 0; n < 4; ++n) acc[m][n] = (f32x4){0.f, 0.f, 0.f, 0.f};

  // staging: chunk c: row c>>2, phys slot c&3; global segment = slot ^ ((row>>1)&3)
  int r1 = tid >> 2, s1 = tid & 3;
  int seg = (s1 ^ ((r1 >> 1) & 3)) * 8;
  const unsigned short* gA1 = Ab + (size_t)(g0 + r1) * 512 + seg;
  const unsigned short* gA2 = Ab + (size_t)(g0 + r1 + 64) * 512 + seg;
  int vr1 = v0 + r1;      if (vr1 > V - 1) vr1 = V - 1;
  int vr2 = v0 + r1 + 64; if (vr2 > V - 1) vr2 = V - 1;
  const unsigned short* gB1 = Bb + (size_t)vr1 * 512 + seg;
  const unsigned short* gB2 = Bb + (size_t)vr2 * 512 + seg;

  // prologue: stage kt=0 into buf 0
  gload_lds16(gA1, &As[0][wave * 512]);
  gload_lds16(gA2, &As[0][2048 + wave * 512]);
  gload_lds16(gB1, &Bs[0][wave * 512]);
  gload_lds16(gB2, &Bs[0][2048 + wave * 512]);
  gA1 += 32; gA2 += 32; gB1 += 32; gB2 += 32;
  __syncthreads();

  int sl = (rsel >> 1) & 3;   // read-side swizzle term
  int cur = 0;
  for (int kt = 0; kt < 16; ++kt) {
    if (kt + 1 < 16) {
      int nb = cur ^ 1;
      gload_lds16(gA1, &As[nb][wave * 512]);
      gload_lds16(gA2, &As[nb][2048 + wave * 512]);
      gload_lds16(gB1, &Bs[nb][wave * 512]);
      gload_lds16(gB2, &Bs[nb][2048 + wave * 512]);
      gA1 += 32; gA2 += 32; gB1 += 32; gB2 += 32;
    }

    bf16x8 af[4], bfr[4];
    #pragma unroll
    for (int m = 0; m < 4; ++m)
      af[m] = *(const bf16x8*)(&As[cur][(wr * 64 + m * 16 + rsel) * 32 + ((hi ^ sl) * 8)]);
    #pragma unroll
    for (int n = 0; n < 4; ++n)
      bfr[n] = *(const bf16x8*)(&Bs[cur][(wc * 64 + n * 16 + rsel) * 32 + ((hi ^ sl) * 8)]);
    #pragma unroll
    for (int m = 0; m < 4; ++m)
      #pragma unroll
      for (int n = 0; n < 4; ++n)
        acc[m][n] = __builtin_amdgcn_mfma_f32_16x16x32_bf16(af[m], bfr[n], acc[m][n], 0, 0, 0);
    __syncthreads();   // drains t+1 stage + protects buffer reuse
    cur ^= 1;
  }

  #pragma unroll
  for (int m = 0; m < 4; ++m) {
    #pragma unroll
    for (int i = 0; i < 4; ++i) {
      int g = g0 + wr * 64 + m * 16 + hi * 4 + i;
      int b = g >> 5, lt = g & 31;
      if (lt >= S) continue;
      size_t orow = ((size_t)b * S + lt) * V;
      const float* cb = cbase + (size_t)b * V;
      #pragma unroll
      for (int n = 0; n < 4; ++n) {
        int v = v0 + wc * 64 + n * 16 + rsel;
        if (v < V) out[orow + v] = acc[m][n][i] + cb[v];
      }
    }
  }
}

// ---------------------------------------------------------------------------
extern "C" void kernel_launch(void* const* d_in, const int* in_sizes, int n_in,
                              void* d_out, int out_size, void* d_ws, size_t ws_size,
                              hipStream_t stream) {
  const float* features = (const float*)d_in[0];
  const int*   captions = (const int*)d_in[1];
  const float* embed_W  = (const float*)d_in[3];
  const float* W1   = (const float*)d_in[4];
  const float* b1   = (const float*)d_in[5];
  const float* cw1  = (const float*)d_in[6];
  const float* cb1  = (const float*)d_in[7];
  const float* cw2  = (const float*)d_in[8];
  const float* cb2  = (const float*)d_in[9];
  const float* Wenc = (const float*)d_in[10];
  const float* benc = (const float*)d_in[11];
  const float* Wp   = (const float*)d_in[14];
  const float* W2   = (const float*)d_in[16];
  const float* b2   = (const float*)d_in[17];
  float* out = (float*)d_out;

  float* ws = (float*)d_ws;
  float* wv       = ws;                 // 1024
  float* c0       = ws + 1024;          // 16
  unsigned short* enc_meanb = (unsigned short*)(ws + 1040);  // 65536 bf16
  unsigned short* ctxb = (unsigned short*)(ws + 66576);      // 65536 bf16
  float* xA       = ws + 164880;        // 1048576 (x1; dead after GLU1)
  float* xB       = ws + 1213456;       // 1048576 (x2)
  float* y        = ws + 2262032;       // 2097152 (conv GEMM out; cbase aliases)
  float* cbase    = y;                  // 1920000 <= 2097152
  unsigned short* x3b  = (unsigned short*)xA;             // 1048576 bf16 (xA dead)
  unsigned short* Xc   = (unsigned short*)(ws + 4359184); // 7340032 bf16
  unsigned short* wbuf = (unsigned short*)(ws + 8029200); // 3670016 bf16
  unsigned short* W2d  = (unsigned short*)(ws + 9864208); // 15360000 bf16
  // Xe / w1b live inside the Xc region (free until im2col layer 1)
  unsigned short* Xe  = Xc;                  // 1048576 bf16
  unsigned short* w1b = Xc + 1048576;        // 786432 bf16 (full W1)
  // end: 17,544,208 floats = 70.2 MB (unchanged)

  hipLaunchKernelGGL(k_cvt_w2d,  dim3(15000),   dim3(256), 0, stream, W2, W2d);
  hipLaunchKernelGGL(k_wv,       dim3(4),       dim3(256), 0, stream, Wenc, Wp, benc, wv, c0);
  hipLaunchKernelGGL(k_mean_ctx, dim3(B),       dim3(256), 0, stream, features, wv, c0, enc_meanb, ctxb);

  // x1 = b1 + [enc_mean||emb] @ W1ᵀ  (fused MFMA, K=1536)
  hipLaunchKernelGGL(k_gather_emb, dim3(2048),  dim3(256), 0, stream, embed_W, captions, Xe);
  hipLaunchKernelGGL(k_cvt_w1,     dim3(512),   dim3(256), 0, stream, W1, w1b);
  hipLaunchKernelGGL(k_x1f_mfma,   dim3(8, 32), dim3(256), 0, stream, enc_meanb, Xe, w1b, b1, xA);

  // conv layer 1
  hipLaunchKernelGGL(k_cvt_wconv, dim3(1024),   dim3(256), 0, stream, cw1, wbuf);
  hipLaunchKernelGGL(k_im2col,    dim3(2048),   dim3(256), 0, stream, xA, Xc);
  hipLaunchKernelGGL(k_conv_mfma, dim3(16, 32), dim3(256), 0, stream, Xc, wbuf, cb1, y);
  hipLaunchKernelGGL(k_glu,       dim3(1024),   dim3(256), 0, stream, y, xA, xB);

  // conv layer 2
  hipLaunchKernelGGL(k_cvt_wconv, dim3(1024),   dim3(256), 0, stream, cw2, wbuf);
  hipLaunchKernelGGL(k_im2col,    dim3(2048),   dim3(256), 0, stream, xB, Xc);
  hipLaunchKernelGGL(k_conv_mfma, dim3(16, 32), dim3(256), 0, stream, Xc, wbuf, cb2, y);
  hipLaunchKernelGGL(k_glu_bf16,  dim3(1024),   dim3(256), 0, stream, y, xB, x3b);

  hipLaunchKernelGGL(k_cbase_mfma, dim3(235),   dim3(256), 0, stream, ctxb, W2, b2, cbase);
  hipLaunchKernelGGL(k_logits_mfma, dim3(3760), dim3(256), 0, stream, x3b, W2d, cbase, out);
}

// Round 10
// 370.459 us; speedup vs baseline: 1.4131x; 1.0998x over previous
//
#include <hip/hip_runtime.h>
#include <hip/hip_bf16.h>
#include <math.h>

// Sizes (fixed by the problem)
#define B 64
#define T 64
#define E_ENC 1024
#define EMB 512
#define D 512
#define L 32
#define S 31
#define A 512
#define V 30000
#define KSZ 7
#define KC (D * KSZ)   // 3584 = conv GEMM K

typedef __attribute__((ext_vector_type(8))) short bf16x8;
typedef __attribute__((ext_vector_type(4))) float f32x4;

__device__ __forceinline__ unsigned short f2bf(float f) {
  union { float f; unsigned int u; } x; x.f = f;
  unsigned int r = (x.u + 0x7fffu + ((x.u >> 16) & 1u)) >> 16;
  return (unsigned short)r;
}

__device__ __forceinline__ void gload_lds16(const void* g, void* l) {
  __builtin_amdgcn_global_load_lds(
      (const __attribute__((address_space(1))) unsigned int*)g,
      (__attribute__((address_space(3))) unsigned int*)l, 16, 0, 0);
}

// ---------------------------------------------------------------------------
// wv[e] = sum_a Wp[a]*Wenc[a,e];  c0 = sum_a benc[a]*Wp[a]
__global__ void k_wv(const float* __restrict__ Wenc, const float* __restrict__ Wp,
                     const float* __restrict__ benc, float* __restrict__ wv,
                     float* __restrict__ c0) {
  __shared__ float red[256];
  int e = blockIdx.x * 256 + threadIdx.x;
  float s = 0.f;
  for (int a = 0; a < A; ++a) s += Wp[a] * Wenc[(size_t)a * E_ENC + e];
  wv[e] = s;
  if (blockIdx.x == 0) {
    int t = threadIdx.x;
    float v = Wp[t] * benc[t] + Wp[t + 256] * benc[t + 256];
    red[t] = v;
    __syncthreads();
    for (int off = 128; off > 0; off >>= 1) {
      if (t < off) red[t] += red[t + off];
      __syncthreads();
    }
    if (t == 0) c0[0] = red[0];
  }
}

// ---------------------------------------------------------------------------
// Per-b: enc_mean (bf16), fscore -> softmax over t -> ctx (bf16)
__global__ void k_mean_ctx(const float* __restrict__ features, const float* __restrict__ wv,
                           const float* __restrict__ c0, unsigned short* __restrict__ enc_meanb,
                           unsigned short* __restrict__ ctxb) {
  int b = blockIdx.x, tid = threadIdx.x;
  const float* fb = features + (size_t)b * T * E_ENC;
  __shared__ float s_attw[T];

  float m0 = 0, m1 = 0, m2 = 0, m3 = 0;
  for (int t = 0; t < T; ++t) {
    const float* r = fb + t * E_ENC;
    m0 += r[tid]; m1 += r[tid + 256]; m2 += r[tid + 512]; m3 += r[tid + 768];
  }
  size_t eb = (size_t)b * E_ENC;
  enc_meanb[eb + tid]       = f2bf(m0 * (1.f / 64.f));
  enc_meanb[eb + tid + 256] = f2bf(m1 * (1.f / 64.f));
  enc_meanb[eb + tid + 512] = f2bf(m2 * (1.f / 64.f));
  enc_meanb[eb + tid + 768] = f2bf(m3 * (1.f / 64.f));

  {
    int t = tid >> 2, part = tid & 3;
    const float* r = fb + t * E_ENC + part * 256;
    const float* wp = wv + part * 256;
    float s = 0.f;
    for (int e = 0; e < 256; e += 4) {
      float4 f4 = *(const float4*)(r + e);
      float4 w4 = *(const float4*)(wp + e);
      s += f4.x * w4.x + f4.y * w4.y + f4.z * w4.z + f4.w * w4.w;
    }
    s += __shfl_xor(s, 1);
    s += __shfl_xor(s, 2);
    if (part == 0) s_attw[t] = s + c0[0];
  }
  __syncthreads();
  if (tid < 64) {
    float v = s_attw[tid];
    float mx = v;
    #pragma unroll
    for (int off = 32; off > 0; off >>= 1) mx = fmaxf(mx, __shfl_xor(mx, off));
    float e = expf(v - mx);
    float sm = e;
    #pragma unroll
    for (int off = 32; off > 0; off >>= 1) sm += __shfl_xor(sm, off);
    s_attw[tid] = e / sm;
  }
  __syncthreads();
  float ca = 0, cb = 0, cc = 0, cd = 0;
  for (int t = 0; t < T; ++t) {
    float w = s_attw[t];
    const float* r = fb + t * E_ENC;
    ca += w * r[tid]; cb += w * r[tid + 256]; cc += w * r[tid + 512]; cd += w * r[tid + 768];
  }
  ctxb[eb + tid]       = f2bf(ca);
  ctxb[eb + tid + 256] = f2bf(cb);
  ctxb[eb + tid + 512] = f2bf(cc);
  ctxb[eb + tid + 768] = f2bf(cd);
}

// ---------------------------------------------------------------------------
// Gather embedding rows per caption token -> bf16 Xe[2048][512]
__global__ void k_gather_emb(const float* __restrict__ embed_W,
                             const int* __restrict__ captions,
                             unsigned short* __restrict__ Xe) {
  int g = blockIdx.x, tid = threadIdx.x;
  int cap = captions[g];
  const float* src = embed_W + (size_t)cap * EMB;
  float2 v = *(const float2*)(src + tid * 2);
  unsigned int pk = (unsigned int)f2bf(v.x) | ((unsigned int)f2bf(v.y) << 16);
  *(unsigned int*)(Xe + (size_t)g * EMB + tid * 2) = pk;
}

// Full W1 conversion: w1b[d][k] = bf16(W1[d][k])
__global__ void k_cvt_w1(const float* __restrict__ W1, unsigned short* __restrict__ w1b) {
  int d = blockIdx.x, tid = threadIdx.x;
  #pragma unroll
  for (int i = 0; i < 3; ++i) {
    int c = tid * 2 + i * 512;
    float2 v = *(const float2*)(W1 + (size_t)d * (E_ENC + EMB) + c);
    unsigned int pk = (unsigned int)f2bf(v.x) | ((unsigned int)f2bf(v.y) << 16);
    *(unsigned int*)(w1b + (size_t)d * (E_ENC + EMB) + c) = pk;
  }
}

// ---------------------------------------------------------------------------
// Fused x1 GEMM: x1[g][d] = b1[d] + [enc_mean(b)||emb(g)] . w1b[d,:]
__global__ __launch_bounds__(256) void k_x1f_mfma(
    const unsigned short* __restrict__ enc_meanb,  // [64][1024] bf16
    const unsigned short* __restrict__ Xe,         // [2048][512] bf16
    const unsigned short* __restrict__ w1b,        // [512][1536] bf16
    const float* __restrict__ b1, float* __restrict__ x1) {
  __shared__ __align__(16) unsigned short As[64 * 64];  // 8 KB
  __shared__ __align__(16) unsigned short Bs[64 * 64];  // 8 KB
  int c0 = blockIdx.x * 64, g0 = blockIdx.y * 64;
  int tid = threadIdx.x, lane = tid & 63, wave = tid >> 6;
  int wr = wave >> 1, wc = wave & 1;
  int rsel = lane & 15, hi = lane >> 4;

  f32x4 acc[2][2];
  #pragma unroll
  for (int m = 0; m < 2; ++m)
    #pragma unroll
    for (int n = 0; n < 2; ++n) acc[m][n] = (f32x4){0.f, 0.f, 0.f, 0.f};

  int r1 = tid >> 3, s1 = tid & 7;
  int sw = (s1 ^ (r1 & 7)) * 8;
  const unsigned short* emA1 = enc_meanb + (size_t)(g0 >> 5) * 1024 + sw;
  const unsigned short* emA2 = enc_meanb + (size_t)((g0 >> 5) + 1) * 1024 + sw;
  const unsigned short* xeA1 = Xe + (size_t)(g0 + r1) * 512 + sw;
  const unsigned short* xeA2 = Xe + (size_t)(g0 + r1 + 32) * 512 + sw;
  const unsigned short* gB1 = w1b + (size_t)(c0 + r1) * (E_ENC + EMB) + sw;
  const unsigned short* gB2 = w1b + (size_t)(c0 + r1 + 32) * (E_ENC + EMB) + sw;
  unsigned short* aD1 = As + wave * 512;
  unsigned short* aD2 = As + 2048 + wave * 512;
  unsigned short* bD1 = Bs + wave * 512;
  unsigned short* bD2 = Bs + 2048 + wave * 512;

  int slot0 = hi ^ (rsel & 7);
  int slot1 = (4 + hi) ^ (rsel & 7);

  for (int kt = 0; kt < 24; ++kt) {
    const unsigned short *pA1, *pA2;
    if (kt < 16) { pA1 = emA1 + kt * 64; pA2 = emA2 + kt * 64; }
    else         { pA1 = xeA1 + (kt - 16) * 64; pA2 = xeA2 + (kt - 16) * 64; }
    gload_lds16(pA1, aD1);
    gload_lds16(pA2, aD2);
    gload_lds16(gB1, bD1);
    gload_lds16(gB2, bD2);
    gB1 += 64; gB2 += 64;
    __syncthreads();

    bf16x8 af[2][2], bfr[2][2];
    #pragma unroll
    for (int m = 0; m < 2; ++m) {
      int rowA = (wr * 32 + m * 16 + rsel) * 64;
      af[m][0] = *(const bf16x8*)(As + rowA + slot0 * 8);
      af[m][1] = *(const bf16x8*)(As + rowA + slot1 * 8);
    }
    #pragma unroll
    for (int n = 0; n < 2; ++n) {
      int rowB = (wc * 32 + n * 16 + rsel) * 64;
      bfr[n][0] = *(const bf16x8*)(Bs + rowB + slot0 * 8);
      bfr[n][1] = *(const bf16x8*)(Bs + rowB + slot1 * 8);
    }
    #pragma unroll
    for (int m = 0; m < 2; ++m)
      #pragma unroll
      for (int n = 0; n < 2; ++n) {
        acc[m][n] = __builtin_amdgcn_mfma_f32_16x16x32_bf16(af[m][0], bfr[n][0], acc[m][n], 0, 0, 0);
        acc[m][n] = __builtin_amdgcn_mfma_f32_16x16x32_bf16(af[m][1], bfr[n][1], acc[m][n], 0, 0, 0);
      }
    __syncthreads();
  }

  float bvv[2];
  #pragma unroll
  for (int n = 0; n < 2; ++n) bvv[n] = b1[c0 + wc * 32 + n * 16 + rsel];
  #pragma unroll
  for (int m = 0; m < 2; ++m)
    #pragma unroll
    for (int i = 0; i < 4; ++i) {
      int g = g0 + wr * 32 + m * 16 + hi * 4 + i;
      float* xr = x1 + (size_t)g * D;
      #pragma unroll
      for (int n = 0; n < 2; ++n) {
        int c = c0 + wc * 32 + n * 16 + rsel;
        xr[c] = acc[m][n][i] + bvv[n];
      }
    }
}

// ---------------------------------------------------------------------------
// im2col: Xc[g][k*512+dp] = (l+k-6 >= 0) ? x[b][l+k-6][dp] : 0   (bf16)
__global__ void k_im2col(const float* __restrict__ x, unsigned short* __restrict__ Xc) {
  int g = blockIdx.x, tid = threadIdx.x;
  int b = g >> 5, l = g & 31;
  unsigned short* row = Xc + (size_t)g * KC;
  const float* xb = x + (size_t)b * L * D;
  int d = tid * 2;
  #pragma unroll
  for (int k = 0; k < KSZ; ++k) {
    int lp = l + k - 6;
    unsigned int pk = 0;
    if (lp >= 0) {
      float2 v = *(const float2*)(xb + (size_t)lp * D + d);
      pk = (unsigned int)f2bf(v.x) | ((unsigned int)f2bf(v.y) << 16);
    }
    *(unsigned int*)(row + k * 512 + d) = pk;
  }
}

// ---------------------------------------------------------------------------
// conv weight reorder+convert: wb[c][k*512+dp] = bf16(w[c][dp*7+k])
__global__ void k_cvt_wconv(const float* __restrict__ w, unsigned short* __restrict__ wb) {
  __shared__ float row[KC];  // 14 KiB
  int c = blockIdx.x, tid = threadIdx.x;
  const float* wr = w + (size_t)c * KC;
  for (int i = tid; i < KC; i += 256) row[i] = wr[i];
  __syncthreads();
  unsigned short* ob = wb + (size_t)c * KC;
  int dp = tid * 2;
  #pragma unroll
  for (int k = 0; k < KSZ; ++k) {
    unsigned int pk = (unsigned int)f2bf(row[dp * 7 + k]) |
                      ((unsigned int)f2bf(row[(dp + 1) * 7 + k]) << 16);
    *(unsigned int*)(ob + k * 512 + dp) = pk;
  }
}

// ---------------------------------------------------------------------------
// Fused Conv GEMM + GLU + residual.
// Block: 32 d-cols x 64 g-rows. B-rows 0..31 = gate ch c0+r; 32..63 = sigmoid
// ch 512+c0+r. wc=1 waves publish sigmoid inputs via LDS (reused dbuf space);
// wc=0 waves compute a*sigmoid(b)+res and write xout directly.
template <int OUT_BF16>
__global__ __launch_bounds__(256) void k_conv_glu(
    const unsigned short* __restrict__ Xc, const unsigned short* __restrict__ wb,
    const float* __restrict__ bias, const float* __restrict__ xres,
    float* __restrict__ outf, unsigned short* __restrict__ outh) {
  __shared__ __align__(16) unsigned char csmem[32768];
  unsigned short (*As)[64 * 64] = (unsigned short (*)[64 * 64])csmem;          // [2]
  unsigned short (*Bs)[64 * 64] = (unsigned short (*)[64 * 64])(csmem + 16384); // [2]
  int c0 = blockIdx.x * 32, g0 = blockIdx.y * 64;
  int tid = threadIdx.x, lane = tid & 63, wave = tid >> 6;
  int wr = wave >> 1, wc = wave & 1;
  int rsel = lane & 15, hi = lane >> 4;

  f32x4 acc[2][2];
  #pragma unroll
  for (int m = 0; m < 2; ++m)
    #pragma unroll
    for (int n = 0; n < 2; ++n) acc[m][n] = (f32x4){0.f, 0.f, 0.f, 0.f};

  int r1 = tid >> 3, s1 = tid & 7;
  int sw = (s1 ^ (r1 & 7)) * 8;              // swizzled global k-segment
  const unsigned short* gA1 = Xc + (size_t)(g0 + r1) * KC + sw;
  const unsigned short* gA2 = Xc + (size_t)(g0 + r1 + 32) * KC + sw;
  const unsigned short* gB1 = wb + (size_t)(c0 + r1) * KC + sw;            // gate
  const unsigned short* gB2 = wb + (size_t)(512 + c0 + r1) * KC + sw;      // sigmoid

  int slot0 = hi ^ (rsel & 7);
  int slot1 = (4 + hi) ^ (rsel & 7);

  gload_lds16(gA1, &As[0][wave * 512]);
  gload_lds16(gA2, &As[0][2048 + wave * 512]);
  gload_lds16(gB1, &Bs[0][wave * 512]);
  gload_lds16(gB2, &Bs[0][2048 + wave * 512]);
  gA1 += 64; gA2 += 64; gB1 += 64; gB2 += 64;
  __syncthreads();

  int cur = 0;
  for (int kt = 0; kt < KC / 64; ++kt) {
    if (kt + 1 < KC / 64) {
      int nb = cur ^ 1;
      gload_lds16(gA1, &As[nb][wave * 512]);
      gload_lds16(gA2, &As[nb][2048 + wave * 512]);
      gload_lds16(gB1, &Bs[nb][wave * 512]);
      gload_lds16(gB2, &Bs[nb][2048 + wave * 512]);
      gA1 += 64; gA2 += 64; gB1 += 64; gB2 += 64;
    }

    bf16x8 af[2][2], bfr[2][2];
    #pragma unroll
    for (int m = 0; m < 2; ++m) {
      int rowA = (wr * 32 + m * 16 + rsel) * 64;
      af[m][0] = *(const bf16x8*)(&As[cur][rowA + slot0 * 8]);
      af[m][1] = *(const bf16x8*)(&As[cur][rowA + slot1 * 8]);
    }
    #pragma unroll
    for (int n = 0; n < 2; ++n) {
      int rowB = (wc * 32 + n * 16 + rsel) * 64;
      bfr[n][0] = *(const bf16x8*)(&Bs[cur][rowB + slot0 * 8]);
      bfr[n][1] = *(const bf16x8*)(&Bs[cur][rowB + slot1 * 8]);
    }
    #pragma unroll
    for (int m = 0; m < 2; ++m)
      #pragma unroll
      for (int n = 0; n < 2; ++n) {
        acc[m][n] = __builtin_amdgcn_mfma_f32_16x16x32_bf16(af[m][0], bfr[n][0], acc[m][n], 0, 0, 0);
        acc[m][n] = __builtin_amdgcn_mfma_f32_16x16x32_bf16(af[m][1], bfr[n][1], acc[m][n], 0, 0, 0);
      }
    __syncthreads();
    cur ^= 1;
  }

  // Epilogue: GLU + residual. LDS dbuf is dead — reuse as sb[64][33] fp32.
  float* sb = (float*)csmem;
  float bvv[2];
  #pragma unroll
  for (int n = 0; n < 2; ++n)
    bvv[n] = wc ? bias[512 + c0 + n * 16 + rsel] : bias[c0 + n * 16 + rsel];
  if (wc) {
    #pragma unroll
    for (int m = 0; m < 2; ++m)
      #pragma unroll
      for (int i = 0; i < 4; ++i) {
        int lr = wr * 32 + m * 16 + hi * 4 + i;
        #pragma unroll
        for (int n = 0; n < 2; ++n)
          sb[lr * 33 + n * 16 + rsel] = acc[m][n][i] + bvv[n];
      }
  }
  __syncthreads();
  if (!wc) {
    #pragma unroll
    for (int m = 0; m < 2; ++m)
      #pragma unroll
      for (int i = 0; i < 4; ++i) {
        int lr = wr * 32 + m * 16 + hi * 4 + i;
        int g = g0 + lr;
        const float* xr = xres + (size_t)g * 512 + c0;
        #pragma unroll
        for (int n = 0; n < 2; ++n) {
          int d = n * 16 + rsel;
          float ya = acc[m][n][i] + bvv[n];
          float yb = sb[lr * 33 + d];
          float val = ya / (1.f + expf(-yb)) + xr[d];
          if (OUT_BF16) outh[(size_t)g * 512 + c0 + d] = f2bf(val);
          else          outf[(size_t)g * 512 + c0 + d] = val;
        }
      }
  }
}

// ---------------------------------------------------------------------------
// cbase[b,v] = b2[v] + ctx[b,:1024] . W2[v,:1024]  as bf16 MFMA.
__global__ __launch_bounds__(256) void k_cbase_mfma(
    const unsigned short* __restrict__ ctxb,  // [64][1024] bf16
    const float* __restrict__ W2,             // [30000][1536] fp32
    const float* __restrict__ b2, float* __restrict__ cbase) {
  __shared__ __align__(16) unsigned short As[64 * 64];    // 8 KB
  __shared__ __align__(16) unsigned short Bs[128 * 64];   // 16 KB
  int v0 = blockIdx.x * 128;
  int tid = threadIdx.x, lane = tid & 63, wave = tid >> 6;
  int rsel = lane & 15, hi = lane >> 4;
  int wc = wave;

  f32x4 acc[4][2];
  #pragma unroll
  for (int m = 0; m < 4; ++m)
    #pragma unroll
    for (int n = 0; n < 2; ++n) acc[m][n] = (f32x4){0.f, 0.f, 0.f, 0.f};

  int ra1 = tid >> 3, sa = tid & 7;
  int ra2 = ra1 + 32;
  const unsigned short* gA1 = ctxb + (size_t)ra1 * 1024 + (sa ^ (ra1 & 7)) * 8;
  const unsigned short* gA2 = ctxb + (size_t)ra2 * 1024 + (sa ^ (ra2 & 7)) * 8;
  unsigned short* aD1 = As + wave * 512;
  unsigned short* aD2 = As + 2048 + wave * 512;

  const float* gB[4];
  int bofs[4];
  #pragma unroll
  for (int p = 0; p < 4; ++p) {
    int row = p * 32 + (tid >> 3);
    int seg = tid & 7;
    int vr = v0 + row; if (vr > V - 1) vr = V - 1;
    gB[p] = W2 + (size_t)vr * (E_ENC + D) + seg * 8;
    bofs[p] = row * 64 + (seg ^ (row & 7)) * 8;
  }

  for (int kt = 0; kt < 16; ++kt) {
    gload_lds16(gA1, aD1);
    gload_lds16(gA2, aD2);
    gA1 += 64; gA2 += 64;
    #pragma unroll
    for (int p = 0; p < 4; ++p) {
      float4 f0 = *(const float4*)(gB[p]);
      float4 f1 = *(const float4*)(gB[p] + 4);
      gB[p] += 64;
      bf16x8 o;
      o[0] = (short)f2bf(f0.x); o[1] = (short)f2bf(f0.y);
      o[2] = (short)f2bf(f0.z); o[3] = (short)f2bf(f0.w);
      o[4] = (short)f2bf(f1.x); o[5] = (short)f2bf(f1.y);
      o[6] = (short)f2bf(f1.z); o[7] = (short)f2bf(f1.w);
      *(bf16x8*)(Bs + bofs[p]) = o;
    }
    __syncthreads();

    bf16x8 af[4][2], bfr[2][2];
    #pragma unroll
    for (int m = 0; m < 4; ++m) {
      int rowA = (m * 16 + rsel) * 64;
      #pragma unroll
      for (int kk = 0; kk < 2; ++kk)
        af[m][kk] = *(const bf16x8*)(As + rowA + ((kk * 4 + hi) ^ (rsel & 7)) * 8);
    }
    #pragma unroll
    for (int n = 0; n < 2; ++n) {
      int rowB = (wc * 32 + n * 16 + rsel) * 64;
      #pragma unroll
      for (int kk = 0; kk < 2; ++kk)
        bfr[n][kk] = *(const bf16x8*)(Bs + rowB + ((kk * 4 + hi) ^ (rsel & 7)) * 8);
    }
    #pragma unroll
    for (int kk = 0; kk < 2; ++kk)
      #pragma unroll
      for (int m = 0; m < 4; ++m)
        #pragma unroll
        for (int n = 0; n < 2; ++n)
          acc[m][n] = __builtin_amdgcn_mfma_f32_16x16x32_bf16(af[m][kk], bfr[n][kk], acc[m][n], 0, 0, 0);
    __syncthreads();
  }

  #pragma unroll
  for (int n = 0; n < 2; ++n) {
    int v = v0 + wc * 32 + n * 16 + rsel;
    if (v >= V) continue;
    float bias = b2[v];
    #pragma unroll
    for (int m = 0; m < 4; ++m)
      #pragma unroll
      for (int i = 0; i < 4; ++i) {
        int b = m * 16 + hi * 4 + i;
        cbase[(size_t)b * V + v] = acc[m][n][i] + bias;
      }
  }
}

// ---------------------------------------------------------------------------
// W2 decode-half conversion: y[v][c] = bf16(W2[v][1024+c])
__global__ void k_cvt_w2d(const float* __restrict__ W2, unsigned short* __restrict__ y) {
  int i = blockIdx.x * 256 + threadIdx.x;
  int row = i >> 7, c = (i & 127) << 2;
  float4 f = *(const float4*)(W2 + (size_t)row * (E_ENC + D) + E_ENC + c);
  ushort4 o;
  o.x = f2bf(f.x); o.y = f2bf(f.y); o.z = f2bf(f.z); o.w = f2bf(f.w);
  *(ushort4*)(y + (size_t)row * D + c) = o;
}

// ---------------------------------------------------------------------------
// logits[b,s,v] = cbase[b,v] + x3[b,s,:] . W2d[v,:]
// BK=32, 4-slot XOR swizzle, 2-phase dbuf @32KB, XCD-bijective remap,
// + LDS-transposed float4 epilogue (reuses the dead dbuf LDS).
__global__ __launch_bounds__(256) void k_logits_mfma(
    const unsigned short* __restrict__ Ab,   // x3 bf16 [2048][512]
    const unsigned short* __restrict__ Bb,   // W2d bf16 [30000][512]
    const float* __restrict__ cbase, float* __restrict__ out) {
  __shared__ __align__(16) unsigned char smem[33792];  // dbuf 32KB | ebuf 64x132 f32
  unsigned short (*As)[128 * 32] = (unsigned short (*)[128 * 32])smem;           // [2]
  unsigned short (*Bs)[128 * 32] = (unsigned short (*)[128 * 32])(smem + 16384); // [2]
  int flat = blockIdx.x;                  // 3760 = 8 * 470
  int ord = (flat & 7) * 470 + (flat >> 3);
  int v0 = (ord >> 4) * 128, g0 = (ord & 15) * 128;
  int tid = threadIdx.x, lane = tid & 63, wave = tid >> 6;
  int wr = wave >> 1, wc = wave & 1;
  int rsel = lane & 15, hi = lane >> 4;

  f32x4 acc[4][4];
  #pragma unroll
  for (int m = 0; m < 4; ++m)
    #pragma unroll
    for (int n = 0; n < 4; ++n) acc[m][n] = (f32x4){0.f, 0.f, 0.f, 0.f};

  int r1 = tid >> 2, s1 = tid & 3;
  int seg = (s1 ^ ((r1 >> 1) & 3)) * 8;
  const unsigned short* gA1 = Ab + (size_t)(g0 + r1) * 512 + seg;
  const unsigned short* gA2 = Ab + (size_t)(g0 + r1 + 64) * 512 + seg;
  int vr1 = v0 + r1;      if (vr1 > V - 1) vr1 = V - 1;
  int vr2 = v0 + r1 + 64; if (vr2 > V - 1) vr2 = V - 1;
  const unsigned short* gB1 = Bb + (size_t)vr1 * 512 + seg;
  const unsigned short* gB2 = Bb + (size_t)vr2 * 512 + seg;

  gload_lds16(gA1, &As[0][wave * 512]);
  gload_lds16(gA2, &As[0][2048 + wave * 512]);
  gload_lds16(gB1, &Bs[0][wave * 512]);
  gload_lds16(gB2, &Bs[0][2048 + wave * 512]);
  gA1 += 32; gA2 += 32; gB1 += 32; gB2 += 32;
  __syncthreads();

  int sl = (rsel >> 1) & 3;
  int cur = 0;
  for (int kt = 0; kt < 16; ++kt) {
    if (kt + 1 < 16) {
      int nb = cur ^ 1;
      gload_lds16(gA1, &As[nb][wave * 512]);
      gload_lds16(gA2, &As[nb][2048 + wave * 512]);
      gload_lds16(gB1, &Bs[nb][wave * 512]);
      gload_lds16(gB2, &Bs[nb][2048 + wave * 512]);
      gA1 += 32; gA2 += 32; gB1 += 32; gB2 += 32;
    }

    bf16x8 af[4], bfr[4];
    #pragma unroll
    for (int m = 0; m < 4; ++m)
      af[m] = *(const bf16x8*)(&As[cur][(wr * 64 + m * 16 + rsel) * 32 + ((hi ^ sl) * 8)]);
    #pragma unroll
    for (int n = 0; n < 4; ++n)
      bfr[n] = *(const bf16x8*)(&Bs[cur][(wc * 64 + n * 16 + rsel) * 32 + ((hi ^ sl) * 8)]);
    #pragma unroll
    for (int m = 0; m < 4; ++m)
      #pragma unroll
      for (int n = 0; n < 4; ++n)
        acc[m][n] = __builtin_amdgcn_mfma_f32_16x16x32_bf16(af[m], bfr[n], acc[m][n], 0, 0, 0);
    __syncthreads();
    cur ^= 1;
  }

  // Epilogue: LDS transpose (dbuf dead) -> float4 coalesced stores.
  float* ebuf = (float*)smem;   // [64][132]
  #pragma unroll
  for (int h = 0; h < 2; ++h) {
    if (h) __syncthreads();
    if (wr == h) {
      #pragma unroll
      for (int m = 0; m < 4; ++m)
        #pragma unroll
        for (int i = 0; i < 4; ++i) {
          int lr = m * 16 + hi * 4 + i;
          #pragma unroll
          for (int n = 0; n < 4; ++n)
            ebuf[lr * 132 + wc * 64 + n * 16 + rsel] = acc[m][n][i];
        }
    }
    __syncthreads();
    #pragma unroll
    for (int j = 0; j < 8; ++j) {
      int f = tid + j * 256;
      int lr = f >> 5, c4 = (f & 31) * 4;
      int g = g0 + h * 64 + lr;
      int b = g >> 5, lt = g & 31;
      int v = v0 + c4;
      if (lt < S && v < V) {
        float4 val = *(const float4*)(ebuf + lr * 132 + c4);
        float4 cb4 = *(const float4*)(cbase + (size_t)b * V + v);
        float4 o;
        o.x = val.x + cb4.x; o.y = val.y + cb4.y;
        o.z = val.z + cb4.z; o.w = val.w + cb4.w;
        *(float4*)(out + ((size_t)b * S + lt) * V + v) = o;
      }
    }
  }
}

// ---------------------------------------------------------------------------
extern "C" void kernel_launch(void* const* d_in, const int* in_sizes, int n_in,
                              void* d_out, int out_size, void* d_ws, size_t ws_size,
                              hipStream_t stream) {
  const float* features = (const float*)d_in[0];
  const int*   captions = (const int*)d_in[1];
  const float* embed_W  = (const float*)d_in[3];
  const float* W1   = (const float*)d_in[4];
  const float* b1   = (const float*)d_in[5];
  const float* cw1  = (const float*)d_in[6];
  const float* cb1  = (const float*)d_in[7];
  const float* cw2  = (const float*)d_in[8];
  const float* cb2  = (const float*)d_in[9];
  const float* Wenc = (const float*)d_in[10];
  const float* benc = (const float*)d_in[11];
  const float* Wp   = (const float*)d_in[14];
  const float* W2   = (const float*)d_in[16];
  const float* b2   = (const float*)d_in[17];
  float* out = (float*)d_out;

  float* ws = (float*)d_ws;
  float* wv       = ws;                 // 1024
  float* c0       = ws + 1024;          // 16
  unsigned short* enc_meanb = (unsigned short*)(ws + 1040);  // 65536 bf16
  unsigned short* ctxb = (unsigned short*)(ws + 66576);      // 65536 bf16
  float* xA       = ws + 164880;        // 1048576 (x1; x3b overlays later)
  float* xB       = ws + 1213456;       // 1048576 (x2)
  float* cbase    = ws + 2262032;       // 1920000
  unsigned short* x3b  = (unsigned short*)xA;             // 1048576 bf16 (xA dead)
  unsigned short* Xc   = (unsigned short*)(ws + 4359184); // 7340032 bf16
  unsigned short* wbuf = (unsigned short*)(ws + 8029200); // 3670016 bf16
  unsigned short* W2d  = (unsigned short*)(ws + 9864208); // 15360000 bf16
  unsigned short* Xe  = Xc;                  // 1048576 bf16 (pre-im2col)
  unsigned short* w1b = Xc + 1048576;        // 786432 bf16 (full W1)
  // end: 17,544,208 floats = 70.2 MB (unchanged)

  hipLaunchKernelGGL(k_cvt_w2d,  dim3(15000),   dim3(256), 0, stream, W2, W2d);
  hipLaunchKernelGGL(k_wv,       dim3(4),       dim3(256), 0, stream, Wenc, Wp, benc, wv, c0);
  hipLaunchKernelGGL(k_mean_ctx, dim3(B),       dim3(256), 0, stream, features, wv, c0, enc_meanb, ctxb);

  // x1 = b1 + [enc_mean||emb] @ W1ᵀ  (fused MFMA, K=1536)
  hipLaunchKernelGGL(k_gather_emb, dim3(2048),  dim3(256), 0, stream, embed_W, captions, Xe);
  hipLaunchKernelGGL(k_cvt_w1,     dim3(512),   dim3(256), 0, stream, W1, w1b);
  hipLaunchKernelGGL(k_x1f_mfma,   dim3(8, 32), dim3(256), 0, stream, enc_meanb, Xe, w1b, b1, xA);

  // conv layer 1 (GEMM+GLU fused; writes gated+res fp32 into xB)
  hipLaunchKernelGGL(k_cvt_wconv,   dim3(1024),   dim3(256), 0, stream, cw1, wbuf);
  hipLaunchKernelGGL(k_im2col,      dim3(2048),   dim3(256), 0, stream, xA, Xc);
  hipLaunchKernelGGL(k_conv_glu<0>, dim3(16, 32), dim3(256), 0, stream, Xc, wbuf, cb1, xA, xB, (unsigned short*)nullptr);

  // conv layer 2 (writes bf16 x3 directly)
  hipLaunchKernelGGL(k_cvt_wconv,   dim3(1024),   dim3(256), 0, stream, cw2, wbuf);
  hipLaunchKernelGGL(k_im2col,      dim3(2048),   dim3(256), 0, stream, xB, Xc);
  hipLaunchKernelGGL(k_conv_glu<1>, dim3(16, 32), dim3(256), 0, stream, Xc, wbuf, cb2, xB, (float*)nullptr, x3b);

  hipLaunchKernelGGL(k_cbase_mfma, dim3(235),   dim3(256), 0, stream, ctxb, W2, b2, cbase);
  hipLaunchKernelGGL(k_logits_mfma, dim3(3760), dim3(256), 0, stream, x3b, W2d, cbase, out);
}

// Round 11
// 368.329 us; speedup vs baseline: 1.4212x; 1.0058x over previous
//
#include <hip/hip_runtime.h>
#include <hip/hip_bf16.h>
#include <math.h>

// Sizes (fixed by the problem)
#define B 64
#define T 64
#define E_ENC 1024
#define EMB 512
#define D 512
#define L 32
#define S 31
#define A 512
#define V 30000
#define KSZ 7
#define KC (D * KSZ)   // 3584 = conv GEMM K

typedef __attribute__((ext_vector_type(8))) short bf16x8;
typedef __attribute__((ext_vector_type(4))) float f32x4;

__device__ __forceinline__ unsigned short f2bf(float f) {
  union { float f; unsigned int u; } x; x.f = f;
  unsigned int r = (x.u + 0x7fffu + ((x.u >> 16) & 1u)) >> 16;
  return (unsigned short)r;
}

__device__ __forceinline__ void gload_lds16(const void* g, void* l) {
  __builtin_amdgcn_global_load_lds(
      (const __attribute__((address_space(1))) unsigned int*)g,
      (__attribute__((address_space(3))) unsigned int*)l, 16, 0, 0);
}

// ---------------------------------------------------------------------------
// wv[e] = sum_a Wp[a]*Wenc[a,e];  c0 = sum_a benc[a]*Wp[a]
// 16 blocks x 256 threads: 64 e's per block, 4-way a-split, LDS reduce.
__global__ void k_wv(const float* __restrict__ Wenc, const float* __restrict__ Wp,
                     const float* __restrict__ benc, float* __restrict__ wv,
                     float* __restrict__ c0) {
  __shared__ float sp[4][64];
  __shared__ float red[256];
  int el = threadIdx.x & 63, part = threadIdx.x >> 6;
  int e = blockIdx.x * 64 + el;
  float s = 0.f;
  for (int a = part * 128; a < part * 128 + 128; ++a)
    s += Wp[a] * Wenc[(size_t)a * E_ENC + e];
  sp[part][el] = s;
  __syncthreads();
  if (part == 0) wv[e] = sp[0][el] + sp[1][el] + sp[2][el] + sp[3][el];
  if (blockIdx.x == 0) {
    int t = threadIdx.x;
    float v = Wp[t] * benc[t] + Wp[t + 256] * benc[t + 256];
    red[t] = v;
    __syncthreads();
    for (int off = 128; off > 0; off >>= 1) {
      if (t < off) red[t] += red[t + off];
      __syncthreads();
    }
    if (t == 0) c0[0] = red[0];
  }
}

// ---------------------------------------------------------------------------
// Per-b: enc_mean (bf16), fscore -> softmax over t -> ctx (bf16)
__global__ void k_mean_ctx(const float* __restrict__ features, const float* __restrict__ wv,
                           const float* __restrict__ c0, unsigned short* __restrict__ enc_meanb,
                           unsigned short* __restrict__ ctxb) {
  int b = blockIdx.x, tid = threadIdx.x;
  const float* fb = features + (size_t)b * T * E_ENC;
  __shared__ float s_attw[T];

  float m0 = 0, m1 = 0, m2 = 0, m3 = 0;
  for (int t = 0; t < T; ++t) {
    const float* r = fb + t * E_ENC;
    m0 += r[tid]; m1 += r[tid + 256]; m2 += r[tid + 512]; m3 += r[tid + 768];
  }
  size_t eb = (size_t)b * E_ENC;
  enc_meanb[eb + tid]       = f2bf(m0 * (1.f / 64.f));
  enc_meanb[eb + tid + 256] = f2bf(m1 * (1.f / 64.f));
  enc_meanb[eb + tid + 512] = f2bf(m2 * (1.f / 64.f));
  enc_meanb[eb + tid + 768] = f2bf(m3 * (1.f / 64.f));

  {
    int t = tid >> 2, part = tid & 3;
    const float* r = fb + t * E_ENC + part * 256;
    const float* wp = wv + part * 256;
    float s = 0.f;
    for (int e = 0; e < 256; e += 4) {
      float4 f4 = *(const float4*)(r + e);
      float4 w4 = *(const float4*)(wp + e);
      s += f4.x * w4.x + f4.y * w4.y + f4.z * w4.z + f4.w * w4.w;
    }
    s += __shfl_xor(s, 1);
    s += __shfl_xor(s, 2);
    if (part == 0) s_attw[t] = s + c0[0];
  }
  __syncthreads();
  if (tid < 64) {
    float v = s_attw[tid];
    float mx = v;
    #pragma unroll
    for (int off = 32; off > 0; off >>= 1) mx = fmaxf(mx, __shfl_xor(mx, off));
    float e = expf(v - mx);
    float sm = e;
    #pragma unroll
    for (int off = 32; off > 0; off >>= 1) sm += __shfl_xor(sm, off);
    s_attw[tid] = e / sm;
  }
  __syncthreads();
  float ca = 0, cb = 0, cc = 0, cd = 0;
  for (int t = 0; t < T; ++t) {
    float w = s_attw[t];
    const float* r = fb + t * E_ENC;
    ca += w * r[tid]; cb += w * r[tid + 256]; cc += w * r[tid + 512]; cd += w * r[tid + 768];
  }
  ctxb[eb + tid]       = f2bf(ca);
  ctxb[eb + tid + 256] = f2bf(cb);
  ctxb[eb + tid + 512] = f2bf(cc);
  ctxb[eb + tid + 768] = f2bf(cd);
}

// ---------------------------------------------------------------------------
// Gather embedding rows per caption token -> bf16 Xe[2048][512]
__global__ void k_gather_emb(const float* __restrict__ embed_W,
                             const int* __restrict__ captions,
                             unsigned short* __restrict__ Xe) {
  int g = blockIdx.x, tid = threadIdx.x;
  int cap = captions[g];
  const float* src = embed_W + (size_t)cap * EMB;
  float2 v = *(const float2*)(src + tid * 2);
  unsigned int pk = (unsigned int)f2bf(v.x) | ((unsigned int)f2bf(v.y) << 16);
  *(unsigned int*)(Xe + (size_t)g * EMB + tid * 2) = pk;
}

// Full W1 conversion: w1b[d][k] = bf16(W1[d][k])
__global__ void k_cvt_w1(const float* __restrict__ W1, unsigned short* __restrict__ w1b) {
  int d = blockIdx.x, tid = threadIdx.x;
  #pragma unroll
  for (int i = 0; i < 3; ++i) {
    int c = tid * 2 + i * 512;
    float2 v = *(const float2*)(W1 + (size_t)d * (E_ENC + EMB) + c);
    unsigned int pk = (unsigned int)f2bf(v.x) | ((unsigned int)f2bf(v.y) << 16);
    *(unsigned int*)(w1b + (size_t)d * (E_ENC + EMB) + c) = pk;
  }
}

// ---------------------------------------------------------------------------
// Fused x1 GEMM: x1[g][d] = b1[d] + [enc_mean(b)||emb(g)] . w1b[d,:]
__global__ __launch_bounds__(256) void k_x1f_mfma(
    const unsigned short* __restrict__ enc_meanb,  // [64][1024] bf16
    const unsigned short* __restrict__ Xe,         // [2048][512] bf16
    const unsigned short* __restrict__ w1b,        // [512][1536] bf16
    const float* __restrict__ b1, float* __restrict__ x1) {
  __shared__ __align__(16) unsigned short As[64 * 64];  // 8 KB
  __shared__ __align__(16) unsigned short Bs[64 * 64];  // 8 KB
  int c0 = blockIdx.x * 64, g0 = blockIdx.y * 64;
  int tid = threadIdx.x, lane = tid & 63, wave = tid >> 6;
  int wr = wave >> 1, wc = wave & 1;
  int rsel = lane & 15, hi = lane >> 4;

  f32x4 acc[2][2];
  #pragma unroll
  for (int m = 0; m < 2; ++m)
    #pragma unroll
    for (int n = 0; n < 2; ++n) acc[m][n] = (f32x4){0.f, 0.f, 0.f, 0.f};

  int r1 = tid >> 3, s1 = tid & 7;
  int sw = (s1 ^ (r1 & 7)) * 8;
  const unsigned short* emA1 = enc_meanb + (size_t)(g0 >> 5) * 1024 + sw;
  const unsigned short* emA2 = enc_meanb + (size_t)((g0 >> 5) + 1) * 1024 + sw;
  const unsigned short* xeA1 = Xe + (size_t)(g0 + r1) * 512 + sw;
  const unsigned short* xeA2 = Xe + (size_t)(g0 + r1 + 32) * 512 + sw;
  const unsigned short* gB1 = w1b + (size_t)(c0 + r1) * (E_ENC + EMB) + sw;
  const unsigned short* gB2 = w1b + (size_t)(c0 + r1 + 32) * (E_ENC + EMB) + sw;
  unsigned short* aD1 = As + wave * 512;
  unsigned short* aD2 = As + 2048 + wave * 512;
  unsigned short* bD1 = Bs + wave * 512;
  unsigned short* bD2 = Bs + 2048 + wave * 512;

  int slot0 = hi ^ (rsel & 7);
  int slot1 = (4 + hi) ^ (rsel & 7);

  for (int kt = 0; kt < 24; ++kt) {
    const unsigned short *pA1, *pA2;
    if (kt < 16) { pA1 = emA1 + kt * 64; pA2 = emA2 + kt * 64; }
    else         { pA1 = xeA1 + (kt - 16) * 64; pA2 = xeA2 + (kt - 16) * 64; }
    gload_lds16(pA1, aD1);
    gload_lds16(pA2, aD2);
    gload_lds16(gB1, bD1);
    gload_lds16(gB2, bD2);
    gB1 += 64; gB2 += 64;
    __syncthreads();

    bf16x8 af[2][2], bfr[2][2];
    #pragma unroll
    for (int m = 0; m < 2; ++m) {
      int rowA = (wr * 32 + m * 16 + rsel) * 64;
      af[m][0] = *(const bf16x8*)(As + rowA + slot0 * 8);
      af[m][1] = *(const bf16x8*)(As + rowA + slot1 * 8);
    }
    #pragma unroll
    for (int n = 0; n < 2; ++n) {
      int rowB = (wc * 32 + n * 16 + rsel) * 64;
      bfr[n][0] = *(const bf16x8*)(Bs + rowB + slot0 * 8);
      bfr[n][1] = *(const bf16x8*)(Bs + rowB + slot1 * 8);
    }
    #pragma unroll
    for (int m = 0; m < 2; ++m)
      #pragma unroll
      for (int n = 0; n < 2; ++n) {
        acc[m][n] = __builtin_amdgcn_mfma_f32_16x16x32_bf16(af[m][0], bfr[n][0], acc[m][n], 0, 0, 0);
        acc[m][n] = __builtin_amdgcn_mfma_f32_16x16x32_bf16(af[m][1], bfr[n][1], acc[m][n], 0, 0, 0);
      }
    __syncthreads();
  }

  float bvv[2];
  #pragma unroll
  for (int n = 0; n < 2; ++n) bvv[n] = b1[c0 + wc * 32 + n * 16 + rsel];
  #pragma unroll
  for (int m = 0; m < 2; ++m)
    #pragma unroll
    for (int i = 0; i < 4; ++i) {
      int g = g0 + wr * 32 + m * 16 + hi * 4 + i;
      float* xr = x1 + (size_t)g * D;
      #pragma unroll
      for (int n = 0; n < 2; ++n) {
        int c = c0 + wc * 32 + n * 16 + rsel;
        xr[c] = acc[m][n][i] + bvv[n];
      }
    }
}

// ---------------------------------------------------------------------------
// im2col: Xc[g][k*512+dp] = (l+k-6 >= 0) ? x[b][l+k-6][dp] : 0   (bf16)
__global__ void k_im2col(const float* __restrict__ x, unsigned short* __restrict__ Xc) {
  int g = blockIdx.x, tid = threadIdx.x;
  int b = g >> 5, l = g & 31;
  unsigned short* row = Xc + (size_t)g * KC;
  const float* xb = x + (size_t)b * L * D;
  int d = tid * 2;
  #pragma unroll
  for (int k = 0; k < KSZ; ++k) {
    int lp = l + k - 6;
    unsigned int pk = 0;
    if (lp >= 0) {
      float2 v = *(const float2*)(xb + (size_t)lp * D + d);
      pk = (unsigned int)f2bf(v.x) | ((unsigned int)f2bf(v.y) << 16);
    }
    *(unsigned int*)(row + k * 512 + d) = pk;
  }
}

// ---------------------------------------------------------------------------
// conv weight reorder+convert: wb[c][k*512+dp] = bf16(w[c][dp*7+k])
__global__ void k_cvt_wconv(const float* __restrict__ w, unsigned short* __restrict__ wb) {
  __shared__ float row[KC];  // 14 KiB
  int c = blockIdx.x, tid = threadIdx.x;
  const float* wr = w + (size_t)c * KC;
  for (int i = tid; i < KC; i += 256) row[i] = wr[i];
  __syncthreads();
  unsigned short* ob = wb + (size_t)c * KC;
  int dp = tid * 2;
  #pragma unroll
  for (int k = 0; k < KSZ; ++k) {
    unsigned int pk = (unsigned int)f2bf(row[dp * 7 + k]) |
                      ((unsigned int)f2bf(row[(dp + 1) * 7 + k]) << 16);
    *(unsigned int*)(ob + k * 512 + dp) = pk;
  }
}

// ---------------------------------------------------------------------------
// Fused Conv GEMM + GLU + residual.
template <int OUT_BF16>
__global__ __launch_bounds__(256) void k_conv_glu(
    const unsigned short* __restrict__ Xc, const unsigned short* __restrict__ wb,
    const float* __restrict__ bias, const float* __restrict__ xres,
    float* __restrict__ outf, unsigned short* __restrict__ outh) {
  __shared__ __align__(16) unsigned char csmem[32768];
  unsigned short (*As)[64 * 64] = (unsigned short (*)[64 * 64])csmem;          // [2]
  unsigned short (*Bs)[64 * 64] = (unsigned short (*)[64 * 64])(csmem + 16384); // [2]
  int c0 = blockIdx.x * 32, g0 = blockIdx.y * 64;
  int tid = threadIdx.x, lane = tid & 63, wave = tid >> 6;
  int wr = wave >> 1, wc = wave & 1;
  int rsel = lane & 15, hi = lane >> 4;

  f32x4 acc[2][2];
  #pragma unroll
  for (int m = 0; m < 2; ++m)
    #pragma unroll
    for (int n = 0; n < 2; ++n) acc[m][n] = (f32x4){0.f, 0.f, 0.f, 0.f};

  int r1 = tid >> 3, s1 = tid & 7;
  int sw = (s1 ^ (r1 & 7)) * 8;              // swizzled global k-segment
  const unsigned short* gA1 = Xc + (size_t)(g0 + r1) * KC + sw;
  const unsigned short* gA2 = Xc + (size_t)(g0 + r1 + 32) * KC + sw;
  const unsigned short* gB1 = wb + (size_t)(c0 + r1) * KC + sw;            // gate
  const unsigned short* gB2 = wb + (size_t)(512 + c0 + r1) * KC + sw;      // sigmoid

  int slot0 = hi ^ (rsel & 7);
  int slot1 = (4 + hi) ^ (rsel & 7);

  gload_lds16(gA1, &As[0][wave * 512]);
  gload_lds16(gA2, &As[0][2048 + wave * 512]);
  gload_lds16(gB1, &Bs[0][wave * 512]);
  gload_lds16(gB2, &Bs[0][2048 + wave * 512]);
  gA1 += 64; gA2 += 64; gB1 += 64; gB2 += 64;
  __syncthreads();

  int cur = 0;
  for (int kt = 0; kt < KC / 64; ++kt) {
    if (kt + 1 < KC / 64) {
      int nb = cur ^ 1;
      gload_lds16(gA1, &As[nb][wave * 512]);
      gload_lds16(gA2, &As[nb][2048 + wave * 512]);
      gload_lds16(gB1, &Bs[nb][wave * 512]);
      gload_lds16(gB2, &Bs[nb][2048 + wave * 512]);
      gA1 += 64; gA2 += 64; gB1 += 64; gB2 += 64;
    }

    bf16x8 af[2][2], bfr[2][2];
    #pragma unroll
    for (int m = 0; m < 2; ++m) {
      int rowA = (wr * 32 + m * 16 + rsel) * 64;
      af[m][0] = *(const bf16x8*)(&As[cur][rowA + slot0 * 8]);
      af[m][1] = *(const bf16x8*)(&As[cur][rowA + slot1 * 8]);
    }
    #pragma unroll
    for (int n = 0; n < 2; ++n) {
      int rowB = (wc * 32 + n * 16 + rsel) * 64;
      bfr[n][0] = *(const bf16x8*)(&Bs[cur][rowB + slot0 * 8]);
      bfr[n][1] = *(const bf16x8*)(&Bs[cur][rowB + slot1 * 8]);
    }
    #pragma unroll
    for (int m = 0; m < 2; ++m)
      #pragma unroll
      for (int n = 0; n < 2; ++n) {
        acc[m][n] = __builtin_amdgcn_mfma_f32_16x16x32_bf16(af[m][0], bfr[n][0], acc[m][n], 0, 0, 0);
        acc[m][n] = __builtin_amdgcn_mfma_f32_16x16x32_bf16(af[m][1], bfr[n][1], acc[m][n], 0, 0, 0);
      }
    __syncthreads();
    cur ^= 1;
  }

  // Epilogue: GLU + residual. LDS dbuf is dead — reuse as sb[64][33] fp32.
  float* sb = (float*)csmem;
  float bvv[2];
  #pragma unroll
  for (int n = 0; n < 2; ++n)
    bvv[n] = wc ? bias[512 + c0 + n * 16 + rsel] : bias[c0 + n * 16 + rsel];
  if (wc) {
    #pragma unroll
    for (int m = 0; m < 2; ++m)
      #pragma unroll
      for (int i = 0; i < 4; ++i) {
        int lr = wr * 32 + m * 16 + hi * 4 + i;
        #pragma unroll
        for (int n = 0; n < 2; ++n)
          sb[lr * 33 + n * 16 + rsel] = acc[m][n][i] + bvv[n];
      }
  }
  __syncthreads();
  if (!wc) {
    #pragma unroll
    for (int m = 0; m < 2; ++m)
      #pragma unroll
      for (int i = 0; i < 4; ++i) {
        int lr = wr * 32 + m * 16 + hi * 4 + i;
        int g = g0 + lr;
        const float* xr = xres + (size_t)g * 512 + c0;
        #pragma unroll
        for (int n = 0; n < 2; ++n) {
          int d = n * 16 + rsel;
          float ya = acc[m][n][i] + bvv[n];
          float yb = sb[lr * 33 + d];
          float val = ya / (1.f + expf(-yb)) + xr[d];
          if (OUT_BF16) outh[(size_t)g * 512 + c0 + d] = f2bf(val);
          else          outf[(size_t)g * 512 + c0 + d] = val;
        }
      }
  }
}

// ---------------------------------------------------------------------------
// cbase[b,v] = b2[v] + ctx[b,:1024] . W2[v,:1024]  as bf16 MFMA.
__global__ __launch_bounds__(256) void k_cbase_mfma(
    const unsigned short* __restrict__ ctxb,  // [64][1024] bf16
    const float* __restrict__ W2,             // [30000][1536] fp32
    const float* __restrict__ b2, float* __restrict__ cbase) {
  __shared__ __align__(16) unsigned short As[64 * 64];    // 8 KB
  __shared__ __align__(16) unsigned short Bs[128 * 64];   // 16 KB
  int v0 = blockIdx.x * 128;
  int tid = threadIdx.x, lane = tid & 63, wave = tid >> 6;
  int rsel = lane & 15, hi = lane >> 4;
  int wc = wave;

  f32x4 acc[4][2];
  #pragma unroll
  for (int m = 0; m < 4; ++m)
    #pragma unroll
    for (int n = 0; n < 2; ++n) acc[m][n] = (f32x4){0.f, 0.f, 0.f, 0.f};

  int ra1 = tid >> 3, sa = tid & 7;
  int ra2 = ra1 + 32;
  const unsigned short* gA1 = ctxb + (size_t)ra1 * 1024 + (sa ^ (ra1 & 7)) * 8;
  const unsigned short* gA2 = ctxb + (size_t)ra2 * 1024 + (sa ^ (ra2 & 7)) * 8;
  unsigned short* aD1 = As + wave * 512;
  unsigned short* aD2 = As + 2048 + wave * 512;

  const float* gB[4];
  int bofs[4];
  #pragma unroll
  for (int p = 0; p < 4; ++p) {
    int row = p * 32 + (tid >> 3);
    int seg = tid & 7;
    int vr = v0 + row; if (vr > V - 1) vr = V - 1;
    gB[p] = W2 + (size_t)vr * (E_ENC + D) + seg * 8;
    bofs[p] = row * 64 + (seg ^ (row & 7)) * 8;
  }

  for (int kt = 0; kt < 16; ++kt) {
    gload_lds16(gA1, aD1);
    gload_lds16(gA2, aD2);
    gA1 += 64; gA2 += 64;
    #pragma unroll
    for (int p = 0; p < 4; ++p) {
      float4 f0 = *(const float4*)(gB[p]);
      float4 f1 = *(const float4*)(gB[p] + 4);
      gB[p] += 64;
      bf16x8 o;
      o[0] = (short)f2bf(f0.x); o[1] = (short)f2bf(f0.y);
      o[2] = (short)f2bf(f0.z); o[3] = (short)f2bf(f0.w);
      o[4] = (short)f2bf(f1.x); o[5] = (short)f2bf(f1.y);
      o[6] = (short)f2bf(f1.z); o[7] = (short)f2bf(f1.w);
      *(bf16x8*)(Bs + bofs[p]) = o;
    }
    __syncthreads();

    bf16x8 af[4][2], bfr[2][2];
    #pragma unroll
    for (int m = 0; m < 4; ++m) {
      int rowA = (m * 16 + rsel) * 64;
      #pragma unroll
      for (int kk = 0; kk < 2; ++kk)
        af[m][kk] = *(const bf16x8*)(As + rowA + ((kk * 4 + hi) ^ (rsel & 7)) * 8);
    }
    #pragma unroll
    for (int n = 0; n < 2; ++n) {
      int rowB = (wc * 32 + n * 16 + rsel) * 64;
      #pragma unroll
      for (int kk = 0; kk < 2; ++kk)
        bfr[n][kk] = *(const bf16x8*)(Bs + rowB + ((kk * 4 + hi) ^ (rsel & 7)) * 8);
    }
    #pragma unroll
    for (int kk = 0; kk < 2; ++kk)
      #pragma unroll
      for (int m = 0; m < 4; ++m)
        #pragma unroll
        for (int n = 0; n < 2; ++n)
          acc[m][n] = __builtin_amdgcn_mfma_f32_16x16x32_bf16(af[m][kk], bfr[n][kk], acc[m][n], 0, 0, 0);
    __syncthreads();
  }

  #pragma unroll
  for (int n = 0; n < 2; ++n) {
    int v = v0 + wc * 32 + n * 16 + rsel;
    if (v >= V) continue;
    float bias = b2[v];
    #pragma unroll
    for (int m = 0; m < 4; ++m)
      #pragma unroll
      for (int i = 0; i < 4; ++i) {
        int b = m * 16 + hi * 4 + i;
        cbase[(size_t)b * V + v] = acc[m][n][i] + bias;
      }
  }
}

// ---------------------------------------------------------------------------
// W2 decode-half conversion: y[v][c] = bf16(W2[v][1024+c])
__global__ void k_cvt_w2d(const float* __restrict__ W2, unsigned short* __restrict__ y) {
  int i = blockIdx.x * 256 + threadIdx.x;
  int row = i >> 7, c = (i & 127) << 2;
  float4 f = *(const float4*)(W2 + (size_t)row * (E_ENC + D) + E_ENC + c);
  ushort4 o;
  o.x = f2bf(f.x); o.y = f2bf(f.y); o.z = f2bf(f.z); o.w = f2bf(f.w);
  *(ushort4*)(y + (size_t)row * D + c) = o;
}

// ---------------------------------------------------------------------------
// logits[b,s,v] = cbase[b,v] + x3[b,s,:] . W2d[v,:]
// BK=32, 4-slot XOR swizzle, XCD remap, LDS-transposed float4 epilogue,
// + 3-buffer counted-vmcnt pipeline: stage(t+2) in flight, wait only the
// oldest stage (vmcnt(8)) per step, raw barriers (no full drain).
__global__ __launch_bounds__(256) void k_logits_mfma(
    const unsigned short* __restrict__ Ab,   // x3 bf16 [2048][512]
    const unsigned short* __restrict__ Bb,   // W2d bf16 [30000][512]
    const float* __restrict__ cbase, float* __restrict__ out) {
  __shared__ __align__(16) unsigned char smem[49152];  // 3x(A 8KB + B 8KB); ebuf reuses
  int flat = blockIdx.x;                  // 3760 = 8 * 470
  int ord = (flat & 7) * 470 + (flat >> 3);
  int v0 = (ord >> 4) * 128, g0 = (ord & 15) * 128;
  int tid = threadIdx.x, lane = tid & 63, wave = tid >> 6;
  int wr = wave >> 1, wc = wave & 1;
  int rsel = lane & 15, hi = lane >> 4;

  f32x4 acc[4][4];
  #pragma unroll
  for (int m = 0; m < 4; ++m)
    #pragma unroll
    for (int n = 0; n < 4; ++n) acc[m][n] = (f32x4){0.f, 0.f, 0.f, 0.f};

  // staging: chunk c: row c>>2, phys slot c&3; global segment = slot ^ ((row>>1)&3)
  int r1 = tid >> 2, s1 = tid & 3;
  int seg = (s1 ^ ((r1 >> 1) & 3)) * 8;
  const unsigned short* gA1 = Ab + (size_t)(g0 + r1) * 512 + seg;
  const unsigned short* gA2 = Ab + (size_t)(g0 + r1 + 64) * 512 + seg;
  int vr1 = v0 + r1;      if (vr1 > V - 1) vr1 = V - 1;
  int vr2 = v0 + r1 + 64; if (vr2 > V - 1) vr2 = V - 1;
  const unsigned short* gB1 = Bb + (size_t)vr1 * 512 + seg;
  const unsigned short* gB2 = Bb + (size_t)vr2 * 512 + seg;

  int wofs = wave * 512;

#define L_STAGE(bi)                                                        \
  do {                                                                     \
    unsigned short* aB = (unsigned short*)(smem + (bi) * 8192);            \
    unsigned short* bB = (unsigned short*)(smem + 24576 + (bi) * 8192);    \
    gload_lds16(gA1, aB + wofs);                                           \
    gload_lds16(gA2, aB + 2048 + wofs);                                    \
    gload_lds16(gB1, bB + wofs);                                           \
    gload_lds16(gB2, bB + 2048 + wofs);                                    \
    gA1 += 32; gA2 += 32; gB1 += 32; gB2 += 32;                            \
  } while (0)

  L_STAGE(0);
  L_STAGE(1);

  int sl = (rsel >> 1) & 3;   // read-side swizzle term
  int sidx = 2, cidx = 0;
  for (int kt = 0; kt < 16; ++kt) {
    if (kt < 14) L_STAGE(sidx);
    __builtin_amdgcn_sched_barrier(0);
    if (kt < 14)       asm volatile("s_waitcnt vmcnt(8)" ::: "memory");
    else if (kt == 14) asm volatile("s_waitcnt vmcnt(4)" ::: "memory");
    else               asm volatile("s_waitcnt vmcnt(0)" ::: "memory");
    __builtin_amdgcn_sched_barrier(0);
    __builtin_amdgcn_s_barrier();       // all waves: oldest stage complete
    __builtin_amdgcn_sched_barrier(0);

    const unsigned short* Ac = (const unsigned short*)(smem + cidx * 8192);
    const unsigned short* Bc = (const unsigned short*)(smem + 24576 + cidx * 8192);
    bf16x8 af[4], bfr[4];
    #pragma unroll
    for (int m = 0; m < 4; ++m)
      af[m] = *(const bf16x8*)(Ac + (wr * 64 + m * 16 + rsel) * 32 + ((hi ^ sl) * 8));
    #pragma unroll
    for (int n = 0; n < 4; ++n)
      bfr[n] = *(const bf16x8*)(Bc + (wc * 64 + n * 16 + rsel) * 32 + ((hi ^ sl) * 8));
    #pragma unroll
    for (int m = 0; m < 4; ++m)
      #pragma unroll
      for (int n = 0; n < 4; ++n)
        acc[m][n] = __builtin_amdgcn_mfma_f32_16x16x32_bf16(af[m], bfr[n], acc[m][n], 0, 0, 0);

    __builtin_amdgcn_sched_barrier(0);
    __builtin_amdgcn_s_barrier();       // protect cidx buffer before restage
    sidx = cidx;
    cidx = (cidx + 1 == 3) ? 0 : cidx + 1;
  }
#undef L_STAGE

  // Epilogue: LDS transpose (pipeline LDS dead) -> float4 coalesced stores.
  float* ebuf = (float*)smem;   // [64][132]
  #pragma unroll
  for (int h = 0; h < 2; ++h) {
    if (h) __syncthreads();
    if (wr == h) {
      #pragma unroll
      for (int m = 0; m < 4; ++m)
        #pragma unroll
        for (int i = 0; i < 4; ++i) {
          int lr = m * 16 + hi * 4 + i;
          #pragma unroll
          for (int n = 0; n < 4; ++n)
            ebuf[lr * 132 + wc * 64 + n * 16 + rsel] = acc[m][n][i];
        }
    }
    __syncthreads();
    #pragma unroll
    for (int j = 0; j < 8; ++j) {
      int f = tid + j * 256;
      int lr = f >> 5, c4 = (f & 31) * 4;
      int g = g0 + h * 64 + lr;
      int b = g >> 5, lt = g & 31;
      int v = v0 + c4;
      if (lt < S && v < V) {
        float4 val = *(const float4*)(ebuf + lr * 132 + c4);
        float4 cb4 = *(const float4*)(cbase + (size_t)b * V + v);
        float4 o;
        o.x = val.x + cb4.x; o.y = val.y + cb4.y;
        o.z = val.z + cb4.z; o.w = val.w + cb4.w;
        *(float4*)(out + ((size_t)b * S + lt) * V + v) = o;
      }
    }
  }
}

// ---------------------------------------------------------------------------
extern "C" void kernel_launch(void* const* d_in, const int* in_sizes, int n_in,
                              void* d_out, int out_size, void* d_ws, size_t ws_size,
                              hipStream_t stream) {
  const float* features = (const float*)d_in[0];
  const int*   captions = (const int*)d_in[1];
  const float* embed_W  = (const float*)d_in[3];
  const float* W1   = (const float*)d_in[4];
  const float* b1   = (const float*)d_in[5];
  const float* cw1  = (const float*)d_in[6];
  const float* cb1  = (const float*)d_in[7];
  const float* cw2  = (const float*)d_in[8];
  const float* cb2  = (const float*)d_in[9];
  const float* Wenc = (const float*)d_in[10];
  const float* benc = (const float*)d_in[11];
  const float* Wp   = (const float*)d_in[14];
  const float* W2   = (const float*)d_in[16];
  const float* b2   = (const float*)d_in[17];
  float* out = (float*)d_out;

  float* ws = (float*)d_ws;
  float* wv       = ws;                 // 1024
  float* c0       = ws + 1024;          // 16
  unsigned short* enc_meanb = (unsigned short*)(ws + 1040);  // 65536 bf16
  unsigned short* ctxb = (unsigned short*)(ws + 66576);      // 65536 bf16
  float* xA       = ws + 164880;        // 1048576 (x1; x3b overlays later)
  float* xB       = ws + 1213456;       // 1048576 (x2)
  float* cbase    = ws + 2262032;       // 1920000
  unsigned short* x3b  = (unsigned short*)xA;             // 1048576 bf16 (xA dead)
  unsigned short* Xc   = (unsigned short*)(ws + 4359184); // 7340032 bf16
  unsigned short* wbuf = (unsigned short*)(ws + 8029200); // 3670016 bf16
  unsigned short* W2d  = (unsigned short*)(ws + 9864208); // 15360000 bf16
  unsigned short* Xe  = Xc;                  // 1048576 bf16 (pre-im2col)
  unsigned short* w1b = Xc + 1048576;        // 786432 bf16 (full W1)
  // end: 17,544,208 floats = 70.2 MB (unchanged)

  hipLaunchKernelGGL(k_cvt_w2d,  dim3(15000),   dim3(256), 0, stream, W2, W2d);
  hipLaunchKernelGGL(k_wv,       dim3(16),      dim3(256), 0, stream, Wenc, Wp, benc, wv, c0);
  hipLaunchKernelGGL(k_mean_ctx, dim3(B),       dim3(256), 0, stream, features, wv, c0, enc_meanb, ctxb);

  // x1 = b1 + [enc_mean||emb] @ W1ᵀ  (fused MFMA, K=1536)
  hipLaunchKernelGGL(k_gather_emb, dim3(2048),  dim3(256), 0, stream, embed_W, captions, Xe);
  hipLaunchKernelGGL(k_cvt_w1,     dim3(512),   dim3(256), 0, stream, W1, w1b);
  hipLaunchKernelGGL(k_x1f_mfma,   dim3(8, 32), dim3(256), 0, stream, enc_meanb, Xe, w1b, b1, xA);

  // conv layer 1 (GEMM+GLU fused; writes gated+res fp32 into xB)
  hipLaunchKernelGGL(k_cvt_wconv,   dim3(1024),   dim3(256), 0, stream, cw1, wbuf);
  hipLaunchKernelGGL(k_im2col,      dim3(2048),   dim3(256), 0, stream, xA, Xc);
  hipLaunchKernelGGL(k_conv_glu<0>, dim3(16, 32), dim3(256), 0, stream, Xc, wbuf, cb1, xA, xB, (unsigned short*)nullptr);

  // conv layer 2 (writes bf16 x3 directly)
  hipLaunchKernelGGL(k_cvt_wconv,   dim3(1024),   dim3(256), 0, stream, cw2, wbuf);
  hipLaunchKernelGGL(k_im2col,      dim3(2048),   dim3(256), 0, stream, xB, Xc);
  hipLaunchKernelGGL(k_conv_glu<1>, dim3(16, 32), dim3(256), 0, stream, Xc, wbuf, cb2, xB, (float*)nullptr, x3b);

  hipLaunchKernelGGL(k_cbase_mfma, dim3(235),   dim3(256), 0, stream, ctxb, W2, b2, cbase);
  hipLaunchKernelGGL(k_logits_mfma, dim3(3760), dim3(256), 0, stream, x3b, W2d, cbase, out);
}